// Round 1
// baseline (190.291 us; speedup 1.0000x reference)
//
#include <hip/hip_runtime.h>
#include <hip/hip_bf16.h>

// SimpleTransformer: qkv = x @ W^T + b ; banded causal attention (window 129).
// B=4, T=4096, D=512, HISTORY=128. Inputs fp32, output fp32 (per reference).
// Internally: convert x,W to bf16 once, MFMA-bf16 GEMM + attention, fp32 out.
#define T_SEQ 4096
#define D_DIM 512
#define NBATCH 4
#define HIST 128

typedef short short8 __attribute__((ext_vector_type(8)));   // 8 x bf16 bits (4 VGPRs)
typedef float f32x4 __attribute__((ext_vector_type(4)));

static __device__ __forceinline__ f32x4 mfma_bf16(short8 a, short8 b, f32x4 c) {
  return __builtin_amdgcn_mfma_f32_16x16x32_bf16(a, b, c, 0, 0, 0);
}

static __device__ __forceinline__ ushort f2bf_bits(float f) {
  __hip_bfloat16 h = __float2bfloat16(f);
  return *reinterpret_cast<ushort*>(&h);
}

// Async 16B-per-lane global->LDS DMA. LDS dest is wave-uniform base + lane*16.
static __device__ __forceinline__ void gload_lds16(const ushort* g, ushort* l) {
  __builtin_amdgcn_global_load_lds(
      (__attribute__((address_space(1))) void*)g,
      (__attribute__((address_space(3))) void*)l, 16, 0, 0);
}

// ---------------------------------------------------------------------------
// Kernel 0: fp32 -> bf16 conversion of x (8388608) and W (786432), 8 elems/thread.
// ---------------------------------------------------------------------------
__global__ __launch_bounds__(256)
void cvt_kernel(const float* __restrict__ X, const float* __restrict__ W,
                ushort* __restrict__ Xb, ushort* __restrict__ Wb) {
  constexpr size_t NX = (size_t)NBATCH * T_SEQ * D_DIM;   // 8388608
  const size_t off = ((size_t)blockIdx.x * 256 + threadIdx.x) * 8;
  const float* s;
  ushort* d;
  if (off < NX) { s = X + off; d = Xb + off; }
  else          { s = W + (off - NX); d = Wb + (off - NX); }
  const float4 a = *(const float4*)s;
  const float4 b = *(const float4*)(s + 4);
  short8 v;
  v[0] = f2bf_bits(a.x); v[1] = f2bf_bits(a.y);
  v[2] = f2bf_bits(a.z); v[3] = f2bf_bits(a.w);
  v[4] = f2bf_bits(b.x); v[5] = f2bf_bits(b.y);
  v[6] = f2bf_bits(b.z); v[7] = f2bf_bits(b.w);
  *(short8*)d = v;
}

// ---------------------------------------------------------------------------
// Kernel 1: qkv[m][n] = sum_k X[m][k] * W[n][k] + bias[n]   (bf16 in, fp32 acc)
//   M = 16384, N = 1536, K = 512. Tile 128x128, BK=64, 256 threads (2x2 waves).
//   Staging: global_load_lds dwordx4 (DMA, no VGPR round-trip). LDS dest is
//   LINEAR; the XOR swizzle (kq ^ (m&7)) is applied to the per-lane GLOBAL
//   source address instead (XOR is an involution), so the swizzled
//   ds_read_b128 fragment reads below are unchanged and stay conflict-free.
//   Epilogue: n in [0,512)->Q, [512,1024)->K (row-major bf16),
//             [1024,1536)->V stored transposed as Vt[b][d][t] bf16.
// ---------------------------------------------------------------------------
__global__ __launch_bounds__(256, 2)
void qkv_gemm_kernel(const ushort* __restrict__ X,
                     const ushort* __restrict__ W,
                     const float* __restrict__ bias,
                     ushort* __restrict__ Qo,
                     ushort* __restrict__ Ko,
                     ushort* __restrict__ Vt) {
  constexpr int BK = 64, KD = D_DIM;
  __shared__ __align__(16) ushort sA[128 * BK];   // 16 KB
  __shared__ __align__(16) ushort sB[128 * BK];   // 16 KB

  const int tid  = threadIdx.x;
  const int wave = tid >> 6, lane = tid & 63;
  const int col  = lane & 15, quad = lane >> 4;
  const int m0 = blockIdx.x * 128;
  const int n0 = blockIdx.y * 128;
  const int wm = (wave >> 1) * 64, wn = (wave & 1) * 64;

  // Per-lane pre-swizzled global sources. Wave w stages LDS chunks
  // [w*256, (w+1)*256) over 4 issues; LDS slot c = m*8 + kqs holds global
  // chunk (m, kqs ^ (m&7)).
  const ushort* gA[4];
  const ushort* gB[4];
#pragma unroll
  for (int j = 0; j < 4; ++j) {
    const int c  = wave * 256 + j * 64 + lane;
    const int m  = c >> 3;
    const int kq = (c & 7) ^ (m & 7);
    gA[j] = X + (size_t)(m0 + m) * KD + kq * 8;
    gB[j] = W + (size_t)(n0 + m) * KD + kq * 8;
  }

  f32x4 acc[4][4];
#pragma unroll
  for (int i = 0; i < 4; ++i)
#pragma unroll
    for (int j = 0; j < 4; ++j) acc[i][j] = (f32x4)0.0f;

  for (int k0 = 0; k0 < KD; k0 += BK) {
    __syncthreads();   // previous tile's LDS reads done
#pragma unroll
    for (int j = 0; j < 4; ++j) {
      gload_lds16(gA[j] + k0, &sA[(wave * 256 + j * 64) * 8]);
      gload_lds16(gB[j] + k0, &sB[(wave * 256 + j * 64) * 8]);
    }
    __syncthreads();   // compiler drains vmcnt(0) before s_barrier: data landed
#pragma unroll
    for (int ks = 0; ks < 2; ++ks) {
      const int kq = ks * 4 + quad;
      short8 af[4], bf[4];
#pragma unroll
      for (int mt = 0; mt < 4; ++mt) {
        const int m = wm + mt * 16 + col;
        af[mt] = *(const short8*)(&sA[(m * 8 + (kq ^ (m & 7))) * 8]);
      }
#pragma unroll
      for (int nt = 0; nt < 4; ++nt) {
        const int n = wn + nt * 16 + col;
        bf[nt] = *(const short8*)(&sB[(n * 8 + (kq ^ (n & 7))) * 8]);
      }
#pragma unroll
      for (int mt = 0; mt < 4; ++mt)
#pragma unroll
        for (int nt = 0; nt < 4; ++nt)
          acc[mt][nt] = mfma_bf16(af[mt], bf[nt], acc[mt][nt]);
    }
  }

  const int region = n0 >> 9;   // 0=Q, 1=K, 2=V (tiles never straddle)
#pragma unroll
  for (int nt = 0; nt < 4; ++nt) {
    const int ng = n0 + wn + nt * 16 + col;
    const float bv = bias[ng];
    const int d = ng & (D_DIM - 1);
#pragma unroll
    for (int mt = 0; mt < 4; ++mt) {
      const int mg = m0 + wm + mt * 16 + quad * 4;   // C/D: row = quad*4 + r
#pragma unroll
      for (int r = 0; r < 4; ++r) {
        const ushort hv = f2bf_bits(acc[mt][nt][r] + bv);
        const int mr = mg + r;
        if (region == 0) {
          Qo[(size_t)mr * D_DIM + d] = hv;
        } else if (region == 1) {
          Ko[(size_t)mr * D_DIM + d] = hv;
        } else {
          const int bb = mr >> 12;
          const int tt = mr & (T_SEQ - 1);
          Vt[((size_t)bb * D_DIM + d) * T_SEQ + tt] = hv;
        }
      }
    }
  }
}

// ---------------------------------------------------------------------------
// Kernel 2: banded attention. One block per (batch, 32-query tile), 512 thr.
//   Key span [t0-128, t0+32) = 160 keys; padded col range 192 = 4 waves * 48.
//   8 waves: QK^T split 2 row-groups x 4 col-groups; PV split 8 x 64 d-cols.
//   512 blocks, 37.5 KB LDS -> up to 4 blocks/CU (vs old 1 blk = 1 wave/SIMD).
// ---------------------------------------------------------------------------
__global__ __launch_bounds__(512)
void attn_kernel(const ushort* __restrict__ Qb,
                 const ushort* __restrict__ Kb,
                 const ushort* __restrict__ Vtb,
                 float* __restrict__ out) {
  constexpr int QBLK = 32;
  constexpr int SLD = 193;   // fp32 stride (odd) -> conflict-free softmax sweeps
  constexpr int PLD = 200;   // bf16 stride, 400B rows (16B aligned)
  __shared__ float  S[QBLK * SLD];   // 24704 B
  __shared__ ushort P[QBLK * PLD];   // 12800 B

  const int tid  = threadIdx.x;
  const int wave = tid >> 6, lane = tid & 63;
  const int col  = lane & 15, quad = lane >> 4;
  const int b  = blockIdx.x >> 7;              // 128 tiles per batch
  const int t0 = (blockIdx.x & 127) * QBLK;
  const int s0 = t0 - HIST;

  const ushort* Qp = Qb  + (size_t)b * T_SEQ * D_DIM;
  const ushort* Kp = Kb  + (size_t)b * T_SEQ * D_DIM;
  const ushort* Vp = Vtb + (size_t)b * D_DIM * T_SEQ;

  // ---- phase 1: S[32][192] = Q K^T ----
  const int wg_r = wave >> 2;   // 0..1 : 16-row tile
  const int wg_c = wave & 3;    // 0..3 : 48-col group
  f32x4 sacc[3];
#pragma unroll
  for (int j = 0; j < 3; ++j) sacc[j] = (f32x4)0.0f;

  const int qrow = t0 + wg_r * 16 + col;
#pragma unroll 2
  for (int ks = 0; ks < 16; ++ks) {        // K = 512 = 16 * 32
    const int kk = ks * 32 + quad * 8;
    const short8 af = *(const short8*)(Qp + (size_t)qrow * D_DIM + kk);
    __builtin_amdgcn_s_setprio(1);
#pragma unroll
    for (int st = 0; st < 3; ++st) {
      int sg = s0 + wg_c * 48 + st * 16 + col;
      sg = sg < 0 ? 0 : (sg > T_SEQ - 1 ? T_SEQ - 1 : sg);  // masked in softmax
      const short8 bfr = *(const short8*)(Kp + (size_t)sg * D_DIM + kk);
      sacc[st] = mfma_bf16(af, bfr, sacc[st]);
    }
    __builtin_amdgcn_s_setprio(0);
  }
  const float scale = 0.04419417382415922f;   // 1/sqrt(512)
#pragma unroll
  for (int st = 0; st < 3; ++st) {
    const int c   = wg_c * 48 + st * 16 + col;
    const int row = wg_r * 16 + quad * 4;
#pragma unroll
    for (int r = 0; r < 4; ++r)
      S[(row + r) * SLD + c] = sacc[st][r] * scale;
  }
  __syncthreads();

  // ---- banded softmax: 16 threads per row, 12 cols each ----
  {
    const int row  = tid >> 4, part = tid & 15;
    const int lo = max(row, HIST - t0);   // j_local >= row and key >= 0
    const int hi = row + HIST;            // causal end (<= 159)
    float* Srow = S + row * SLD;
    const int j0 = part * 12;
    float mx = -3.0e38f;
    for (int j = j0; j < j0 + 12; ++j)
      if (j >= lo && j <= hi) mx = fmaxf(mx, Srow[j]);
    mx = fmaxf(mx, __shfl_xor(mx, 1));
    mx = fmaxf(mx, __shfl_xor(mx, 2));
    mx = fmaxf(mx, __shfl_xor(mx, 4));
    mx = fmaxf(mx, __shfl_xor(mx, 8));
    float sum = 0.f;
    for (int j = j0; j < j0 + 12; ++j) {
      if (j >= lo && j <= hi) {
        const float e = __expf(Srow[j] - mx);
        Srow[j] = e;
        sum += e;
      }
    }
    sum += __shfl_xor(sum, 1);
    sum += __shfl_xor(sum, 2);
    sum += __shfl_xor(sum, 4);
    sum += __shfl_xor(sum, 8);
    const float inv = 1.0f / sum;
    ushort* Prow = P + row * PLD;
    for (int j = j0; j < j0 + 12; ++j) {
      const float v = (j >= lo && j <= hi) ? Srow[j] * inv : 0.0f;
      Prow[j] = f2bf_bits(v);
    }
  }
  __syncthreads();

  // ---- phase 2: O[32][512] = P[32][160] @ V[160][512], 64 d-cols per wave ----
#pragma unroll
  for (int nt = 0; nt < 4; ++nt) {
    const int d = wave * 64 + nt * 16 + col;
    f32x4 oacc[2];
    oacc[0] = (f32x4)0.0f;
    oacc[1] = (f32x4)0.0f;
#pragma unroll
    for (int ksv = 0; ksv < 5; ++ksv) {    // 160 = 5 * 32
      int sg = s0 + ksv * 32 + quad * 8;
      sg = sg < 0 ? 0 : sg;                // P is 0 there
      const short8 bfr = *(const short8*)(Vp + (size_t)d * T_SEQ + sg);
      __builtin_amdgcn_s_setprio(1);
#pragma unroll
      for (int mt = 0; mt < 2; ++mt) {
        const short8 af = *(const short8*)(&P[(mt * 16 + col) * PLD + ksv * 32 + quad * 8]);
        oacc[mt] = mfma_bf16(af, bfr, oacc[mt]);
      }
      __builtin_amdgcn_s_setprio(0);
    }
#pragma unroll
    for (int mt = 0; mt < 2; ++mt) {
      const int mg = t0 + mt * 16 + quad * 4;
#pragma unroll
      for (int r = 0; r < 4; ++r)
        out[((size_t)b * T_SEQ + mg + r) * D_DIM + d] = oacc[mt][r];
    }
  }
}

// ---------------------------------------------------------------------------
extern "C" void kernel_launch(void* const* d_in, const int* in_sizes, int n_in,
                              void* d_out, int out_size, void* d_ws, size_t ws_size,
                              hipStream_t stream) {
  const float* X    = (const float*)d_in[0];   // (B*T, 512) fp32
  const float* W    = (const float*)d_in[1];   // (1536, 512) fp32
  const float* bias = (const float*)d_in[2];   // (1536,) fp32

  // ws layout (bf16/ushort): Xb | Wb | Q | K | Vt   (~68.7 MB total)
  const size_t NX = (size_t)NBATCH * T_SEQ * D_DIM;   // 8388608
  const size_t NW = (size_t)3 * D_DIM * D_DIM;        // 786432
  ushort* Xb = (ushort*)d_ws;
  ushort* Wb = Xb + NX;
  ushort* Qw = Wb + NW;
  ushort* Kw = Qw + NX;
  ushort* Vw = Kw + NX;

  {
    const int nchunks = (int)((NX + NW) / 8);          // 1146880
    cvt_kernel<<<nchunks / 256, 256, 0, stream>>>(X, W, Xb, Wb);
  }

  dim3 g1(128, 12), b1(256);   // M/128 = 128, N/128 = 12
  qkv_gemm_kernel<<<g1, b1, 0, stream>>>(Xb, Wb, bias, Qw, Kw, Vw);

  dim3 g2(NBATCH * (T_SEQ / 32)), b2(512);
  attn_kernel<<<g2, b2, 0, stream>>>(Qw, Kw, Vw, (float*)d_out);
}

// Round 2
// 176.709 us; speedup vs baseline: 1.0769x; 1.0769x over previous
//
#include <hip/hip_runtime.h>
#include <hip/hip_bf16.h>

// SimpleTransformer: qkv = x @ W^T + b ; banded causal attention (window 129).
// B=4, T=4096, D=512, HISTORY=128. Inputs fp32, output fp32 (per reference).
// Internally: convert x,W to bf16 once, MFMA-bf16 GEMM + attention, fp32 out.
#define T_SEQ 4096
#define D_DIM 512
#define NBATCH 4
#define HIST 128

typedef short short8 __attribute__((ext_vector_type(8)));   // 8 x bf16 bits (4 VGPRs)
typedef float f32x4 __attribute__((ext_vector_type(4)));

static __device__ __forceinline__ f32x4 mfma_bf16(short8 a, short8 b, f32x4 c) {
  return __builtin_amdgcn_mfma_f32_16x16x32_bf16(a, b, c, 0, 0, 0);
}

static __device__ __forceinline__ ushort f2bf_bits(float f) {
  __hip_bfloat16 h = __float2bfloat16(f);
  return *reinterpret_cast<ushort*>(&h);
}

// Async 16B-per-lane global->LDS DMA. LDS dest is wave-uniform base + lane*16.
static __device__ __forceinline__ void gload_lds16(const ushort* g, ushort* l) {
  __builtin_amdgcn_global_load_lds(
      (__attribute__((address_space(1))) void*)g,
      (__attribute__((address_space(3))) void*)l, 16, 0, 0);
}

// ---------------------------------------------------------------------------
// Kernel 0: fp32 -> bf16 conversion of x (8388608) and W (786432), 8 elems/thread.
// ---------------------------------------------------------------------------
__global__ __launch_bounds__(256)
void cvt_kernel(const float* __restrict__ X, const float* __restrict__ W,
                ushort* __restrict__ Xb, ushort* __restrict__ Wb) {
  constexpr size_t NX = (size_t)NBATCH * T_SEQ * D_DIM;   // 8388608
  const size_t off = ((size_t)blockIdx.x * 256 + threadIdx.x) * 8;
  const float* s;
  ushort* d;
  if (off < NX) { s = X + off; d = Xb + off; }
  else          { s = W + (off - NX); d = Wb + (off - NX); }
  const float4 a = *(const float4*)s;
  const float4 b = *(const float4*)(s + 4);
  short8 v;
  v[0] = f2bf_bits(a.x); v[1] = f2bf_bits(a.y);
  v[2] = f2bf_bits(a.z); v[3] = f2bf_bits(a.w);
  v[4] = f2bf_bits(b.x); v[5] = f2bf_bits(b.y);
  v[6] = f2bf_bits(b.z); v[7] = f2bf_bits(b.w);
  *(short8*)d = v;
}

// ---------------------------------------------------------------------------
// Kernel 1: qkv[m][n] = sum_k X[m][k] * W[n][k] + bias[n]   (bf16 in, fp32 acc)
//   M = 16384, N = 1536, K = 512. Tile 128x128, BK=64, 256 threads (2x2 waves).
//   2-phase double-buffered pipeline (catalog T3-minimum):
//     prologue: STAGE(buf0, t=0); barrier
//     iter t:   STAGE(buf^1, t+1) issued FIRST; ds_read+MFMA from buf;
//               one __syncthreads() (vmcnt(0) drain covered by 32 MFMAs).
//   Staging: global_load_lds dwordx4 (DMA, no VGPR round-trip). LDS dest is
//   LINEAR; the XOR swizzle (kq ^ (m&7)) is applied to the per-lane GLOBAL
//   source address instead (XOR is an involution), so the swizzled
//   ds_read_b128 fragment reads stay conflict-free.
//   Epilogue: n in [0,512)->Q, [512,1024)->K (row-major bf16),
//             [1024,1536)->V stored transposed as Vt[b][d][t] bf16.
// ---------------------------------------------------------------------------
__global__ __launch_bounds__(256, 2)
void qkv_gemm_kernel(const ushort* __restrict__ X,
                     const ushort* __restrict__ W,
                     const float* __restrict__ bias,
                     ushort* __restrict__ Qo,
                     ushort* __restrict__ Ko,
                     ushort* __restrict__ Vt) {
  constexpr int BK = 64, KD = D_DIM;
  constexpr int NT = KD / BK;                       // 8 K-steps
  __shared__ __align__(16) ushort sA[2][128 * BK];  // 2 x 16 KB
  __shared__ __align__(16) ushort sB[2][128 * BK];  // 2 x 16 KB

  const int tid  = threadIdx.x;
  const int wave = tid >> 6, lane = tid & 63;
  const int col  = lane & 15, quad = lane >> 4;
  const int m0 = blockIdx.x * 128;
  const int n0 = blockIdx.y * 128;
  const int wm = (wave >> 1) * 64, wn = (wave & 1) * 64;

  // Per-lane pre-swizzled global sources. Wave w stages LDS chunks
  // [w*256, (w+1)*256) over 4 issues; LDS slot c = m*8 + kqs holds global
  // chunk (m, kqs ^ (m&7)).
  const ushort* gA[4];
  const ushort* gB[4];
#pragma unroll
  for (int j = 0; j < 4; ++j) {
    const int c  = wave * 256 + j * 64 + lane;
    const int m  = c >> 3;
    const int kq = (c & 7) ^ (m & 7);
    gA[j] = X + (size_t)(m0 + m) * KD + kq * 8;
    gB[j] = W + (size_t)(n0 + m) * KD + kq * 8;
  }

  f32x4 acc[4][4];
#pragma unroll
  for (int i = 0; i < 4; ++i)
#pragma unroll
    for (int j = 0; j < 4; ++j) acc[i][j] = (f32x4)0.0f;

  // prologue: stage tile 0 into buffer 0
#pragma unroll
  for (int j = 0; j < 4; ++j) {
    gload_lds16(gA[j], &sA[0][(wave * 256 + j * 64) * 8]);
    gload_lds16(gB[j], &sB[0][(wave * 256 + j * 64) * 8]);
  }
  __syncthreads();   // vmcnt(0) drain + barrier: tile 0 landed

  int cur = 0;
  for (int t = 0; t < NT; ++t) {
    // issue next tile's staging first (into the other buffer)
    if (t < NT - 1) {
      const int k0 = (t + 1) * BK;
#pragma unroll
      for (int j = 0; j < 4; ++j) {
        gload_lds16(gA[j] + k0, &sA[cur ^ 1][(wave * 256 + j * 64) * 8]);
        gload_lds16(gB[j] + k0, &sB[cur ^ 1][(wave * 256 + j * 64) * 8]);
      }
    }
    // compute current tile
    const ushort* cA = sA[cur];
    const ushort* cB = sB[cur];
#pragma unroll
    for (int ks = 0; ks < 2; ++ks) {
      const int kq = ks * 4 + quad;
      short8 af[4], bf[4];
#pragma unroll
      for (int mt = 0; mt < 4; ++mt) {
        const int m = wm + mt * 16 + col;
        af[mt] = *(const short8*)(&cA[(m * 8 + (kq ^ (m & 7))) * 8]);
      }
#pragma unroll
      for (int nt = 0; nt < 4; ++nt) {
        const int n = wn + nt * 16 + col;
        bf[nt] = *(const short8*)(&cB[(n * 8 + (kq ^ (n & 7))) * 8]);
      }
#pragma unroll
      for (int mt = 0; mt < 4; ++mt)
#pragma unroll
        for (int nt = 0; nt < 4; ++nt)
          acc[mt][nt] = mfma_bf16(af[mt], bf[nt], acc[mt][nt]);
    }
    __syncthreads();   // drains this iter's stage; next tile ready
    cur ^= 1;
  }

  const int region = n0 >> 9;   // 0=Q, 1=K, 2=V (tiles never straddle)
#pragma unroll
  for (int nt = 0; nt < 4; ++nt) {
    const int ng = n0 + wn + nt * 16 + col;
    const float bv = bias[ng];
    const int d = ng & (D_DIM - 1);
#pragma unroll
    for (int mt = 0; mt < 4; ++mt) {
      const int mg = m0 + wm + mt * 16 + quad * 4;   // C/D: row = quad*4 + r
#pragma unroll
      for (int r = 0; r < 4; ++r) {
        const ushort hv = f2bf_bits(acc[mt][nt][r] + bv);
        const int mr = mg + r;
        if (region == 0) {
          Qo[(size_t)mr * D_DIM + d] = hv;
        } else if (region == 1) {
          Ko[(size_t)mr * D_DIM + d] = hv;
        } else {
          const int bb = mr >> 12;
          const int tt = mr & (T_SEQ - 1);
          Vt[((size_t)bb * D_DIM + d) * T_SEQ + tt] = hv;
        }
      }
    }
  }
}

// ---------------------------------------------------------------------------
// Kernel 2: banded attention. One block per (batch, 64-query tile).
//   Key span [t0-128, t0+64) = 192 keys = 4 waves * 48 columns.
//   S = Q K^T * scale via MFMA from global (L2-hot); banded softmax in LDS;
//   O = P V via MFMA (P bf16 LDS A-frags, V^T global B-frags); fp32 out.
//   (Reverted to the round-0 structure: 64-row tile keeps 4x operand reuse
//    per global K/V fragment — the QBLK=32 variant halved reuse and
//    regressed ~2.3x.)
// ---------------------------------------------------------------------------
__global__ __launch_bounds__(256)
void attn_kernel(const ushort* __restrict__ Qb,
                 const ushort* __restrict__ Kb,
                 const ushort* __restrict__ Vtb,
                 float* __restrict__ out) {
  constexpr int SLD = 193;   // fp32 stride (odd) -> conflict-free softmax sweeps
  constexpr int PLD = 200;   // bf16 stride, 400B rows (16B aligned)
  __shared__ float  S[64 * SLD];   // 49408 B
  __shared__ ushort P[64 * PLD];   // 25600 B

  const int tid  = threadIdx.x;
  const int wave = tid >> 6, lane = tid & 63;
  const int col  = lane & 15, quad = lane >> 4;
  const int b  = blockIdx.x >> 6;
  const int t0 = (blockIdx.x & 63) * 64;
  const int s0 = t0 - HIST;

  const ushort* Qp = Qb  + (size_t)b * T_SEQ * D_DIM;
  const ushort* Kp = Kb  + (size_t)b * T_SEQ * D_DIM;
  const ushort* Vp = Vtb + (size_t)b * D_DIM * T_SEQ;

  // ---- phase 1: S[64][192] = Q K^T ----
  f32x4 sacc[4][3];
#pragma unroll
  for (int i = 0; i < 4; ++i)
#pragma unroll
    for (int j = 0; j < 3; ++j) sacc[i][j] = (f32x4)0.0f;

#pragma unroll 2
  for (int ks = 0; ks < 16; ++ks) {        // K = 512 = 16 * 32
    const int kk = ks * 32 + quad * 8;
    short8 af[4];
#pragma unroll
    for (int mt = 0; mt < 4; ++mt)
      af[mt] = *(const short8*)(Qp + (size_t)(t0 + mt * 16 + col) * D_DIM + kk);
#pragma unroll
    for (int st = 0; st < 3; ++st) {
      int sg = s0 + wave * 48 + st * 16 + col;
      sg = sg < 0 ? 0 : sg;                // clamped keys masked in softmax
      const short8 bfr = *(const short8*)(Kp + (size_t)sg * D_DIM + kk);
#pragma unroll
      for (int mt = 0; mt < 4; ++mt)
        sacc[mt][st] = mfma_bf16(af[mt], bfr, sacc[mt][st]);
    }
  }
  const float scale = 0.04419417382415922f;   // 1/sqrt(512)
#pragma unroll
  for (int mt = 0; mt < 4; ++mt)
#pragma unroll
    for (int st = 0; st < 3; ++st) {
      const int row = mt * 16 + quad * 4;
      const int c   = wave * 48 + st * 16 + col;
#pragma unroll
      for (int r = 0; r < 4; ++r)
        S[(row + r) * SLD + c] = sacc[mt][st][r] * scale;
    }
  __syncthreads();

  // ---- banded softmax: 4 threads per row, 48 cols each ----
  {
    const int row  = tid >> 2, part = tid & 3;
    const int lo = max(row, HIST - t0);   // j_local >= row and key >= 0
    const int hi = row + HIST;            // causal end (<= 191)
    float* Srow = S + row * SLD;
    const int j0 = part * 48;
    float mx = -3.0e38f;
    for (int j = j0; j < j0 + 48; ++j)
      if (j >= lo && j <= hi) mx = fmaxf(mx, Srow[j]);
    mx = fmaxf(mx, __shfl_xor(mx, 1));
    mx = fmaxf(mx, __shfl_xor(mx, 2));
    float sum = 0.f;
    for (int j = j0; j < j0 + 48; ++j) {
      if (j >= lo && j <= hi) {
        const float e = __expf(Srow[j] - mx);
        Srow[j] = e;
        sum += e;
      }
    }
    sum += __shfl_xor(sum, 1);
    sum += __shfl_xor(sum, 2);
    const float inv = 1.0f / sum;
    ushort* Prow = P + row * PLD;
    for (int j = j0; j < j0 + 48; ++j) {
      const float v = (j >= lo && j <= hi) ? Srow[j] * inv : 0.0f;
      Prow[j] = f2bf_bits(v);
    }
  }
  __syncthreads();

  // ---- phase 2: O[64][512] = P[64][192] @ V[192][512] ----
#pragma unroll 2
  for (int nt = 0; nt < 8; ++nt) {
    const int d = wave * 128 + nt * 16 + col;
    f32x4 oacc[4];
#pragma unroll
    for (int i = 0; i < 4; ++i) oacc[i] = (f32x4)0.0f;
#pragma unroll
    for (int ksv = 0; ksv < 6; ++ksv) {    // 192 = 6 * 32
      int sg = s0 + ksv * 32 + quad * 8;
      sg = sg < 0 ? 0 : sg;                // P is 0 there
      const short8 bfr = *(const short8*)(Vp + (size_t)d * T_SEQ + sg);
#pragma unroll
      for (int mt = 0; mt < 4; ++mt) {
        const short8 af = *(const short8*)(&P[(mt * 16 + col) * PLD + ksv * 32 + quad * 8]);
        oacc[mt] = mfma_bf16(af, bfr, oacc[mt]);
      }
    }
#pragma unroll
    for (int mt = 0; mt < 4; ++mt) {
      const int mg = t0 + mt * 16 + quad * 4;
#pragma unroll
      for (int r = 0; r < 4; ++r)
        out[((size_t)b * T_SEQ + mg + r) * D_DIM + d] = oacc[mt][r];
    }
  }
}

// ---------------------------------------------------------------------------
extern "C" void kernel_launch(void* const* d_in, const int* in_sizes, int n_in,
                              void* d_out, int out_size, void* d_ws, size_t ws_size,
                              hipStream_t stream) {
  const float* X    = (const float*)d_in[0];   // (B*T, 512) fp32
  const float* W    = (const float*)d_in[1];   // (1536, 512) fp32
  const float* bias = (const float*)d_in[2];   // (1536,) fp32

  // ws layout (bf16/ushort): Xb | Wb | Q | K | Vt   (~68.7 MB total)
  const size_t NX = (size_t)NBATCH * T_SEQ * D_DIM;   // 8388608
  const size_t NW = (size_t)3 * D_DIM * D_DIM;        // 786432
  ushort* Xb = (ushort*)d_ws;
  ushort* Wb = Xb + NX;
  ushort* Qw = Wb + NW;
  ushort* Kw = Qw + NX;
  ushort* Vw = Kw + NX;

  {
    const int nchunks = (int)((NX + NW) / 8);          // 1146880
    cvt_kernel<<<nchunks / 256, 256, 0, stream>>>(X, W, Xb, Wb);
  }

  dim3 g1(128, 12), b1(256);   // M/128 = 128, N/128 = 12
  qkv_gemm_kernel<<<g1, b1, 0, stream>>>(Xb, Wb, bias, Qw, Kw, Vw);

  dim3 g2(NBATCH * (T_SEQ / 64)), b2(256);
  attn_kernel<<<g2, b2, 0, stream>>>(Qw, Kw, Vw, (float*)d_out);
}

// Round 3
// 171.282 us; speedup vs baseline: 1.1110x; 1.0317x over previous
//
#include <hip/hip_runtime.h>
#include <hip/hip_bf16.h>

// SimpleTransformer: qkv = x @ W^T + b ; banded causal attention (window 129).
// B=4, T=4096, D=512, HISTORY=128. Inputs fp32, output fp32 (per reference).
// Internally: convert x,W to bf16 once, MFMA-bf16 GEMM + attention, fp32 out.
#define T_SEQ 4096
#define D_DIM 512
#define NBATCH 4
#define HIST 128

typedef short short8 __attribute__((ext_vector_type(8)));   // 8 x bf16 bits (4 VGPRs)
typedef float f32x4 __attribute__((ext_vector_type(4)));

static __device__ __forceinline__ f32x4 mfma_bf16(short8 a, short8 b, f32x4 c) {
  return __builtin_amdgcn_mfma_f32_16x16x32_bf16(a, b, c, 0, 0, 0);
}

static __device__ __forceinline__ ushort f2bf_bits(float f) {
  __hip_bfloat16 h = __float2bfloat16(f);
  return *reinterpret_cast<ushort*>(&h);
}

// Async 16B-per-lane global->LDS DMA. LDS dest is wave-uniform base + lane*16.
static __device__ __forceinline__ void gload_lds16(const ushort* g, ushort* l) {
  __builtin_amdgcn_global_load_lds(
      (__attribute__((address_space(1))) void*)g,
      (__attribute__((address_space(3))) void*)l, 16, 0, 0);
}

// ---------------------------------------------------------------------------
// Kernel 0: fp32 -> bf16 conversion of x (8388608) and W (786432), 8 elems/thread.
// ---------------------------------------------------------------------------
__global__ __launch_bounds__(256)
void cvt_kernel(const float* __restrict__ X, const float* __restrict__ W,
                ushort* __restrict__ Xb, ushort* __restrict__ Wb) {
  constexpr size_t NX = (size_t)NBATCH * T_SEQ * D_DIM;   // 8388608
  const size_t off = ((size_t)blockIdx.x * 256 + threadIdx.x) * 8;
  const float* s;
  ushort* d;
  if (off < NX) { s = X + off; d = Xb + off; }
  else          { s = W + (off - NX); d = Wb + (off - NX); }
  const float4 a = *(const float4*)s;
  const float4 b = *(const float4*)(s + 4);
  short8 v;
  v[0] = f2bf_bits(a.x); v[1] = f2bf_bits(a.y);
  v[2] = f2bf_bits(a.z); v[3] = f2bf_bits(a.w);
  v[4] = f2bf_bits(b.x); v[5] = f2bf_bits(b.y);
  v[6] = f2bf_bits(b.z); v[7] = f2bf_bits(b.w);
  *(short8*)d = v;
}

// ---------------------------------------------------------------------------
// Kernel 1: qkv[m][n] = sum_k X[m][k] * W[n][k] + bias[n]   (bf16 in, fp32 acc)
//   M = 16384, N = 1536, K = 512. Tile 128x128, BK=64, 256 threads (2x2 waves).
//   TRUE 2-deep pipeline (T3+T4): raw s_barrier + COUNTED s_waitcnt vmcnt(8)
//   -- loads for tile t+2 stay in flight across ~2 iterations of compute.
//   __syncthreads() is never used in the loop (it would drain vmcnt(0)).
//   Per iter:
//     vmcnt(8)  : this wave's tile-t loads landed (tile t+1 still flying)
//     barrier   : all waves' tile-t loads landed
//     ds_read all 16 frags of tile t -> regs
//     lgkmcnt(0): reads complete (data in regs)
//     barrier   : all waves done READING buf[t&1]
//     stage tile t+2 into buf[t&1] (8 global_load_lds, NOT waited here)
//     32 MFMAs (setprio 1)
//   Staging via global_load_lds dwordx4; LDS dest LINEAR, XOR swizzle
//   (kq ^ (m&7)) applied to the per-lane GLOBAL source (involution), so the
//   swizzled ds_read_b128 fragment reads stay conflict-free (measured 0).
//   Epilogue: n in [0,512)->Q, [512,1024)->K (row-major bf16),
//             [1024,1536)->V stored transposed as Vt[b][d][t] bf16.
// ---------------------------------------------------------------------------
__global__ __launch_bounds__(256, 2)
void qkv_gemm_kernel(const ushort* __restrict__ X,
                     const ushort* __restrict__ W,
                     const float* __restrict__ bias,
                     ushort* __restrict__ Qo,
                     ushort* __restrict__ Ko,
                     ushort* __restrict__ Vt) {
  constexpr int BK = 64, KD = D_DIM;
  constexpr int NT = KD / BK;                       // 8 K-steps
  __shared__ __align__(16) ushort sA[2][128 * BK];  // 2 x 16 KB
  __shared__ __align__(16) ushort sB[2][128 * BK];  // 2 x 16 KB

  const int tid  = threadIdx.x;
  const int wave = tid >> 6, lane = tid & 63;
  const int col  = lane & 15, quad = lane >> 4;
  const int m0 = blockIdx.x * 128;
  const int n0 = blockIdx.y * 128;
  const int wm = (wave >> 1) * 64, wn = (wave & 1) * 64;

  // Per-lane pre-swizzled global sources. Wave w stages LDS chunks
  // [w*256, (w+1)*256); LDS slot c = m*8 + kqs holds global chunk (m, kqs^(m&7)).
  const ushort* gA[4];
  const ushort* gB[4];
#pragma unroll
  for (int j = 0; j < 4; ++j) {
    const int c  = wave * 256 + j * 64 + lane;
    const int m  = c >> 3;
    const int kq = (c & 7) ^ (m & 7);
    gA[j] = X + (size_t)(m0 + m) * KD + kq * 8;
    gB[j] = W + (size_t)(n0 + m) * KD + kq * 8;
  }

  auto stage = [&](int buf, int t) {
#pragma unroll
    for (int j = 0; j < 4; ++j) {
      gload_lds16(gA[j] + t * BK, &sA[buf][(wave * 256 + j * 64) * 8]);
      gload_lds16(gB[j] + t * BK, &sB[buf][(wave * 256 + j * 64) * 8]);
    }
  };

  f32x4 acc[4][4];
#pragma unroll
  for (int i = 0; i < 4; ++i)
#pragma unroll
    for (int j = 0; j < 4; ++j) acc[i][j] = (f32x4)0.0f;

  // prologue: 2 tiles in flight (16 loads/wave)
  stage(0, 0);
  stage(1, 1);

#pragma unroll
  for (int t = 0; t < NT; ++t) {
    // outstanding loads this wave: 8*(staged - t) = 16 (steady) or 8 (last).
    if (t < NT - 1) asm volatile("s_waitcnt vmcnt(8)" ::: "memory");
    else            asm volatile("s_waitcnt vmcnt(0)" ::: "memory");
    __builtin_amdgcn_s_barrier();        // tile t visible to all waves

    const ushort* cA = sA[t & 1];
    const ushort* cB = sB[t & 1];
    short8 af[2][4], bf[2][4];
#pragma unroll
    for (int ks = 0; ks < 2; ++ks) {
      const int kq = ks * 4 + quad;
#pragma unroll
      for (int mt = 0; mt < 4; ++mt) {
        const int m = wm + mt * 16 + col;
        af[ks][mt] = *(const short8*)(&cA[(m * 8 + (kq ^ (m & 7))) * 8]);
        const int n = wn + mt * 16 + col;
        bf[ks][mt] = *(const short8*)(&cB[(n * 8 + (kq ^ (n & 7))) * 8]);
      }
    }
    asm volatile("s_waitcnt lgkmcnt(0)" ::: "memory");  // reads done (in regs)
    __builtin_amdgcn_s_barrier();        // all waves done reading buf[t&1]

    if (t + 2 < NT) stage(t & 1, t + 2); // overwrite is now safe; not waited

    __builtin_amdgcn_s_setprio(1);
#pragma unroll
    for (int ks = 0; ks < 2; ++ks)
#pragma unroll
      for (int mt = 0; mt < 4; ++mt)
#pragma unroll
        for (int nt = 0; nt < 4; ++nt)
          acc[mt][nt] = mfma_bf16(af[ks][mt], bf[ks][nt], acc[mt][nt]);
    __builtin_amdgcn_s_setprio(0);
  }

  const int region = n0 >> 9;   // 0=Q, 1=K, 2=V (tiles never straddle)
#pragma unroll
  for (int nt = 0; nt < 4; ++nt) {
    const int ng = n0 + wn + nt * 16 + col;
    const float bv = bias[ng];
    const int d = ng & (D_DIM - 1);
#pragma unroll
    for (int mt = 0; mt < 4; ++mt) {
      const int mg = m0 + wm + mt * 16 + quad * 4;   // C/D: row = quad*4 + r
#pragma unroll
      for (int r = 0; r < 4; ++r) {
        const ushort hv = f2bf_bits(acc[mt][nt][r] + bv);
        const int mr = mg + r;
        if (region == 0) {
          Qo[(size_t)mr * D_DIM + d] = hv;
        } else if (region == 1) {
          Ko[(size_t)mr * D_DIM + d] = hv;
        } else {
          const int bb = mr >> 12;
          const int tt = mr & (T_SEQ - 1);
          Vt[((size_t)bb * D_DIM + d) * T_SEQ + tt] = hv;
        }
      }
    }
  }
}

// ---------------------------------------------------------------------------
// Kernel 2: banded attention. One block per (batch, 64-query tile), 512 thr.
//   Same tiling/traffic as the proven round-0 kernel (256 blocks, 64 rows,
//   192-key span) but 8 waves instead of 4: grid is pinned at 1 block/CU,
//   so waves/block is the only TLP lever (1 -> 2 waves/SIMD).
//   QK^T: 2 row-groups x 4 col-groups. PV: 8 waves x 64 d-cols (V-frag
//   reuse across 4 row-tiles preserved).
// ---------------------------------------------------------------------------
__global__ __launch_bounds__(512)
void attn_kernel(const ushort* __restrict__ Qb,
                 const ushort* __restrict__ Kb,
                 const ushort* __restrict__ Vtb,
                 float* __restrict__ out) {
  constexpr int SLD = 193;   // fp32 stride (odd) -> conflict-free softmax sweeps
  constexpr int PLD = 200;   // bf16 stride, 400B rows (16B aligned)
  __shared__ float  S[64 * SLD];   // 49408 B
  __shared__ ushort P[64 * PLD];   // 25600 B

  const int tid  = threadIdx.x;
  const int wave = tid >> 6, lane = tid & 63;
  const int col  = lane & 15, quad = lane >> 4;
  const int b  = blockIdx.x >> 6;
  const int t0 = (blockIdx.x & 63) * 64;
  const int s0 = t0 - HIST;

  const ushort* Qp = Qb  + (size_t)b * T_SEQ * D_DIM;
  const ushort* Kp = Kb  + (size_t)b * T_SEQ * D_DIM;
  const ushort* Vp = Vtb + (size_t)b * D_DIM * T_SEQ;

  // ---- phase 1: S[64][192] = Q K^T ----
  const int wr = wave >> 2;    // 0..1 : 32-row group
  const int wc = wave & 3;     // 0..3 : 48-col group
  f32x4 sacc[2][3];
#pragma unroll
  for (int i = 0; i < 2; ++i)
#pragma unroll
    for (int j = 0; j < 3; ++j) sacc[i][j] = (f32x4)0.0f;

#pragma unroll 2
  for (int ks = 0; ks < 16; ++ks) {        // K = 512 = 16 * 32
    const int kk = ks * 32 + quad * 8;
    short8 af[2];
#pragma unroll
    for (int mt = 0; mt < 2; ++mt)
      af[mt] = *(const short8*)(Qp + (size_t)(t0 + wr * 32 + mt * 16 + col) * D_DIM + kk);
    __builtin_amdgcn_s_setprio(1);
#pragma unroll
    for (int st = 0; st < 3; ++st) {
      int sg = s0 + wc * 48 + st * 16 + col;
      sg = sg < 0 ? 0 : sg;                // clamped keys masked in softmax
      const short8 bfr = *(const short8*)(Kp + (size_t)sg * D_DIM + kk);
#pragma unroll
      for (int mt = 0; mt < 2; ++mt)
        sacc[mt][st] = mfma_bf16(af[mt], bfr, sacc[mt][st]);
    }
    __builtin_amdgcn_s_setprio(0);
  }
  const float scale = 0.04419417382415922f;   // 1/sqrt(512)
#pragma unroll
  for (int mt = 0; mt < 2; ++mt)
#pragma unroll
    for (int st = 0; st < 3; ++st) {
      const int row = wr * 32 + mt * 16 + quad * 4;
      const int c   = wc * 48 + st * 16 + col;
#pragma unroll
      for (int r = 0; r < 4; ++r)
        S[(row + r) * SLD + c] = sacc[mt][st][r] * scale;
    }
  __syncthreads();

  // ---- banded softmax: 8 threads per row, 24 cols each ----
  {
    const int row  = tid >> 3, part = tid & 7;
    const int lo = max(row, HIST - t0);   // j_local >= row and key >= 0
    const int hi = row + HIST;            // causal end (<= 191)
    float* Srow = S + row * SLD;
    const int j0 = part * 24;
    float mx = -3.0e38f;
    for (int j = j0; j < j0 + 24; ++j)
      if (j >= lo && j <= hi) mx = fmaxf(mx, Srow[j]);
    mx = fmaxf(mx, __shfl_xor(mx, 1));
    mx = fmaxf(mx, __shfl_xor(mx, 2));
    mx = fmaxf(mx, __shfl_xor(mx, 4));
    float sum = 0.f;
    for (int j = j0; j < j0 + 24; ++j) {
      if (j >= lo && j <= hi) {
        const float e = __expf(Srow[j] - mx);
        Srow[j] = e;
        sum += e;
      }
    }
    sum += __shfl_xor(sum, 1);
    sum += __shfl_xor(sum, 2);
    sum += __shfl_xor(sum, 4);
    const float inv = 1.0f / sum;
    ushort* Prow = P + row * PLD;
    for (int j = j0; j < j0 + 24; ++j) {
      const float v = (j >= lo && j <= hi) ? Srow[j] * inv : 0.0f;
      Prow[j] = f2bf_bits(v);
    }
  }
  __syncthreads();

  // ---- phase 2: O[64][512] = P[64][192] @ V[192][512], 64 d-cols per wave ----
#pragma unroll
  for (int nt = 0; nt < 4; ++nt) {
    const int d = wave * 64 + nt * 16 + col;
    f32x4 oacc[4];
#pragma unroll
    for (int i = 0; i < 4; ++i) oacc[i] = (f32x4)0.0f;
#pragma unroll
    for (int ksv = 0; ksv < 6; ++ksv) {    // 192 = 6 * 32
      int sg = s0 + ksv * 32 + quad * 8;
      sg = sg < 0 ? 0 : sg;                // P is 0 there
      const short8 bfr = *(const short8*)(Vp + (size_t)d * T_SEQ + sg);
      __builtin_amdgcn_s_setprio(1);
#pragma unroll
      for (int mt = 0; mt < 4; ++mt) {
        const short8 af = *(const short8*)(&P[(mt * 16 + col) * PLD + ksv * 32 + quad * 8]);
        oacc[mt] = mfma_bf16(af, bfr, oacc[mt]);
      }
      __builtin_amdgcn_s_setprio(0);
    }
#pragma unroll
    for (int mt = 0; mt < 4; ++mt) {
      const int mg = t0 + mt * 16 + quad * 4;
#pragma unroll
      for (int r = 0; r < 4; ++r)
        out[((size_t)b * T_SEQ + mg + r) * D_DIM + d] = oacc[mt][r];
    }
  }
}

// ---------------------------------------------------------------------------
extern "C" void kernel_launch(void* const* d_in, const int* in_sizes, int n_in,
                              void* d_out, int out_size, void* d_ws, size_t ws_size,
                              hipStream_t stream) {
  const float* X    = (const float*)d_in[0];   // (B*T, 512) fp32
  const float* W    = (const float*)d_in[1];   // (1536, 512) fp32
  const float* bias = (const float*)d_in[2];   // (1536,) fp32

  // ws layout (bf16/ushort): Xb | Wb | Q | K | Vt   (~68.7 MB total)
  const size_t NX = (size_t)NBATCH * T_SEQ * D_DIM;   // 8388608
  const size_t NW = (size_t)3 * D_DIM * D_DIM;        // 786432
  ushort* Xb = (ushort*)d_ws;
  ushort* Wb = Xb + NX;
  ushort* Qw = Wb + NW;
  ushort* Kw = Qw + NX;
  ushort* Vw = Kw + NX;

  {
    const int nchunks = (int)((NX + NW) / 8);          // 1146880
    cvt_kernel<<<nchunks / 256, 256, 0, stream>>>(X, W, Xb, Wb);
  }

  dim3 g1(128, 12), b1(256);   // M/128 = 128, N/128 = 12
  qkv_gemm_kernel<<<g1, b1, 0, stream>>>(Xb, Wb, bias, Qw, Kw, Vw);

  dim3 g2(NBATCH * (T_SEQ / 64)), b2(512);
  attn_kernel<<<g2, b2, 0, stream>>>(Qw, Kw, Vw, (float*)d_out);
}

// Round 5
// 154.556 us; speedup vs baseline: 1.2312x; 1.1082x over previous
//
#include <hip/hip_runtime.h>
#include <hip/hip_bf16.h>

// SimpleTransformer: qkv = x @ W^T + b ; banded causal attention (window 129).
// B=4, T=4096, D=512, HISTORY=128. Inputs fp32, output fp32 (per reference).
// Internally: convert x,W to bf16 once, MFMA-bf16 GEMM + attention, fp32 out.
#define T_SEQ 4096
#define D_DIM 512
#define NBATCH 4
#define HIST 128

typedef short short8 __attribute__((ext_vector_type(8)));   // 8 x bf16 bits (4 VGPRs)
typedef float f32x4 __attribute__((ext_vector_type(4)));

static __device__ __forceinline__ f32x4 mfma_bf16(short8 a, short8 b, f32x4 c) {
  return __builtin_amdgcn_mfma_f32_16x16x32_bf16(a, b, c, 0, 0, 0);
}

static __device__ __forceinline__ ushort f2bf_bits(float f) {
  __hip_bfloat16 h = __float2bfloat16(f);
  return *reinterpret_cast<ushort*>(&h);
}

// Async 16B-per-lane global->LDS DMA. LDS dest is wave-uniform base + lane*16.
static __device__ __forceinline__ void gload_lds16(const ushort* g, ushort* l) {
  __builtin_amdgcn_global_load_lds(
      (__attribute__((address_space(1))) void*)g,
      (__attribute__((address_space(3))) void*)l, 16, 0, 0);
}

// ---------------------------------------------------------------------------
// Kernel 0: fp32 -> bf16 conversion of x (8388608) and W (786432), 8 elems/thread.
// ---------------------------------------------------------------------------
__global__ __launch_bounds__(256)
void cvt_kernel(const float* __restrict__ X, const float* __restrict__ W,
                ushort* __restrict__ Xb, ushort* __restrict__ Wb) {
  constexpr size_t NX = (size_t)NBATCH * T_SEQ * D_DIM;   // 8388608
  const size_t off = ((size_t)blockIdx.x * 256 + threadIdx.x) * 8;
  const float* s;
  ushort* d;
  if (off < NX) { s = X + off; d = Xb + off; }
  else          { s = W + (off - NX); d = Wb + (off - NX); }
  const float4 a = *(const float4*)s;
  const float4 b = *(const float4*)(s + 4);
  short8 v;
  v[0] = f2bf_bits(a.x); v[1] = f2bf_bits(a.y);
  v[2] = f2bf_bits(a.z); v[3] = f2bf_bits(a.w);
  v[4] = f2bf_bits(b.x); v[5] = f2bf_bits(b.y);
  v[6] = f2bf_bits(b.z); v[7] = f2bf_bits(b.w);
  *(short8*)d = v;
}

// ---------------------------------------------------------------------------
// Kernel 1: qkv[m][n] = sum_k X[m][k] * W[n][k] + bias[n]   (bf16 in, fp32 acc)
//   M = 16384, N = 1536, K = 512. Tile 128x128, BK=64, 256 threads (2x2 waves).
//   K-loop: 2-deep pipeline, raw s_barrier + counted s_waitcnt vmcnt(8).
//   Staging via global_load_lds dwordx4; LDS dest LINEAR, XOR swizzle
//   (kq ^ (m&7)) applied to the per-lane GLOBAL source (involution), so the
//   swizzled ds_read_b128 fragment reads stay conflict-free (measured 0).
//   EPILOGUE: the old path did 64 scalar 2-byte global stores/thread
//   (32B segments -> L2 write-allocate RMW; WRITE_SIZE 95 MB vs 50 ideal).
//   Now each wave stages its 64x64 bf16 tile in LDS (8 KB/wave, reusing sA,
//   per-wave private -> no barrier), then stores short8 = 16 B/lane:
//   Q/K row-major, V transposed in LDS so Vt stores are contiguous in tt.
// ---------------------------------------------------------------------------
__global__ __launch_bounds__(256, 2)
void qkv_gemm_kernel(const ushort* __restrict__ X,
                     const ushort* __restrict__ W,
                     const float* __restrict__ bias,
                     ushort* __restrict__ Qo,
                     ushort* __restrict__ Ko,
                     ushort* __restrict__ Vt) {
  constexpr int BK = 64, KD = D_DIM;
  constexpr int NT = KD / BK;                       // 8 K-steps
  __shared__ __align__(16) ushort sA[2][128 * BK];  // 2 x 16 KB
  __shared__ __align__(16) ushort sB[2][128 * BK];  // 2 x 16 KB

  const int tid  = threadIdx.x;
  const int wave = tid >> 6, lane = tid & 63;
  const int col  = lane & 15, quad = lane >> 4;
  const int m0 = blockIdx.x * 128;
  const int n0 = blockIdx.y * 128;
  const int wm = (wave >> 1) * 64, wn = (wave & 1) * 64;

  // Per-lane pre-swizzled global sources. Wave w stages LDS chunks
  // [w*256, (w+1)*256); LDS slot c = m*8 + kqs holds global chunk (m, kqs^(m&7)).
  const ushort* gA[4];
  const ushort* gB[4];
#pragma unroll
  for (int j = 0; j < 4; ++j) {
    const int c  = wave * 256 + j * 64 + lane;
    const int m  = c >> 3;
    const int kq = (c & 7) ^ (m & 7);
    gA[j] = X + (size_t)(m0 + m) * KD + kq * 8;
    gB[j] = W + (size_t)(n0 + m) * KD + kq * 8;
  }

  auto stage = [&](int buf, int t) {
#pragma unroll
    for (int j = 0; j < 4; ++j) {
      gload_lds16(gA[j] + t * BK, &sA[buf][(wave * 256 + j * 64) * 8]);
      gload_lds16(gB[j] + t * BK, &sB[buf][(wave * 256 + j * 64) * 8]);
    }
  };

  f32x4 acc[4][4];
#pragma unroll
  for (int i = 0; i < 4; ++i)
#pragma unroll
    for (int j = 0; j < 4; ++j) acc[i][j] = (f32x4)0.0f;

  // prologue: 2 tiles in flight (16 loads/wave)
  stage(0, 0);
  stage(1, 1);

#pragma unroll
  for (int t = 0; t < NT; ++t) {
    // outstanding loads this wave: 8*(staged - t) = 16 (steady) or 8 (last).
    if (t < NT - 1) asm volatile("s_waitcnt vmcnt(8)" ::: "memory");
    else            asm volatile("s_waitcnt vmcnt(0)" ::: "memory");
    __builtin_amdgcn_s_barrier();        // tile t visible to all waves

    const ushort* cA = sA[t & 1];
    const ushort* cB = sB[t & 1];
    short8 af[2][4], bf[2][4];
#pragma unroll
    for (int ks = 0; ks < 2; ++ks) {
      const int kq = ks * 4 + quad;
#pragma unroll
      for (int mt = 0; mt < 4; ++mt) {
        const int m = wm + mt * 16 + col;
        af[ks][mt] = *(const short8*)(&cA[(m * 8 + (kq ^ (m & 7))) * 8]);
        const int n = wn + mt * 16 + col;
        bf[ks][mt] = *(const short8*)(&cB[(n * 8 + (kq ^ (n & 7))) * 8]);
      }
    }
    asm volatile("s_waitcnt lgkmcnt(0)" ::: "memory");  // reads done (in regs)
    __builtin_amdgcn_s_barrier();        // all waves done reading buf[t&1]

    if (t + 2 < NT) stage(t & 1, t + 2); // overwrite is now safe; not waited

    __builtin_amdgcn_s_setprio(1);
#pragma unroll
    for (int ks = 0; ks < 2; ++ks)
#pragma unroll
      for (int mt = 0; mt < 4; ++mt)
#pragma unroll
        for (int nt = 0; nt < 4; ++nt)
          acc[mt][nt] = mfma_bf16(af[ks][mt], bf[ks][nt], acc[mt][nt]);
    __builtin_amdgcn_s_setprio(0);
  }

  // ---- epilogue: per-wave 64x64 bf16 tile via LDS, 16B/lane stores ----
  // Per-wave private 8 KB region in sA (all K-loop LDS reads completed at the
  // final barrier above; each wave touches only its own region -> no barrier).
  // Layout: 64 rows x 64 ushort; row R's logical 16B-chunk cq stored at
  // physical chunk cq ^ (R&7)  (keeps both scatter-writes and b128 reads fast).
  ushort* eL = &sA[0][0] + wave * 4096;
  const int region = n0 >> 9;   // 0=Q, 1=K, 2=V (tiles never straddle)

  if (region < 2) {
    // rows = m (row-major output)
#pragma unroll
    for (int nt = 0; nt < 4; ++nt) {
      const float bv = bias[n0 + wn + nt * 16 + col];
      const int cl = nt * 16 + col;               // col_local
#pragma unroll
      for (int mt = 0; mt < 4; ++mt) {
        const int rb = mt * 16 + quad * 4;        // row_local base
#pragma unroll
        for (int r = 0; r < 4; ++r) {
          const int R = rb + r;
          eL[R * 64 + (((cl >> 3) ^ (R & 7)) * 8) + (cl & 7)] =
              f2bf_bits(acc[mt][nt][r] + bv);
        }
      }
    }
    ushort* __restrict__ Out = (region == 0) ? Qo : Ko;
    const int rgrp = lane >> 3, cch = lane & 7;
    const int phys = cch ^ rgrp;                  // (R&7)==rgrp for all j
    const int dbase = (n0 & (D_DIM - 1)) + wn + cch * 8;
#pragma unroll
    for (int j = 0; j < 8; ++j) {
      const int R = j * 8 + rgrp;
      const short8 v = *(const short8*)(&eL[R * 64 + phys * 8]);
      *(short8*)(&Out[(size_t)(m0 + wm + R) * D_DIM + dbase]) = v;
    }
  } else {
    // rows = d (transposed store: Vt[b][d][t] contiguous in t)
#pragma unroll
    for (int nt = 0; nt < 4; ++nt) {
      const float bv = bias[n0 + wn + nt * 16 + col];
      const int dl = nt * 16 + col;               // d_local (LDS row)
#pragma unroll
      for (int mt = 0; mt < 4; ++mt) {
        const int rb = mt * 16 + quad * 4;
#pragma unroll
        for (int r = 0; r < 4; ++r) {
          const int tl = rb + r;                  // tt_local (LDS col)
          eL[dl * 64 + (((tl >> 3) ^ (dl & 7)) * 8) + (tl & 7)] =
              f2bf_bits(acc[mt][nt][r] + bv);
        }
      }
    }
    const int rgrp = lane >> 3, cch = lane & 7;
    const int phys = cch ^ rgrp;
    const int mr0 = m0 + wm;                      // 64-row span, single batch
    const int bb  = mr0 >> 12;
    const int tt0 = (mr0 & (T_SEQ - 1)) + cch * 8;
#pragma unroll
    for (int j = 0; j < 8; ++j) {
      const int dl = j * 8 + rgrp;
      const short8 v = *(const short8*)(&eL[dl * 64 + phys * 8]);
      const int d = (n0 & (D_DIM - 1)) + wn + dl;
      *(short8*)(&Vt[((size_t)bb * D_DIM + d) * T_SEQ + tt0]) = v;
    }
  }
}

// ---------------------------------------------------------------------------
// Kernel 2: banded attention. One block per (batch, 64-query tile), 512 thr.
//   Same tiling/traffic as the proven round-0 kernel (256 blocks, 64 rows,
//   192-key span) but 8 waves: QK^T 2 row-groups x 4 col-groups; PV 8 waves
//   x 64 d-cols (V-frag reuse across 4 row-tiles preserved).
// ---------------------------------------------------------------------------
__global__ __launch_bounds__(512)
void attn_kernel(const ushort* __restrict__ Qb,
                 const ushort* __restrict__ Kb,
                 const ushort* __restrict__ Vtb,
                 float* __restrict__ out) {
  constexpr int SLD = 193;   // fp32 stride (odd) -> conflict-free softmax sweeps
  constexpr int PLD = 200;   // bf16 stride, 400B rows (16B aligned)
  __shared__ float  S[64 * SLD];   // 49408 B
  __shared__ ushort P[64 * PLD];   // 25600 B

  const int tid  = threadIdx.x;
  const int wave = tid >> 6, lane = tid & 63;
  const int col  = lane & 15, quad = lane >> 4;
  const int b  = blockIdx.x >> 6;
  const int t0 = (blockIdx.x & 63) * 64;
  const int s0 = t0 - HIST;

  const ushort* Qp = Qb  + (size_t)b * T_SEQ * D_DIM;
  const ushort* Kp = Kb  + (size_t)b * T_SEQ * D_DIM;
  const ushort* Vp = Vtb + (size_t)b * D_DIM * T_SEQ;

  // ---- phase 1: S[64][192] = Q K^T ----
  const int wr = wave >> 2;    // 0..1 : 32-row group
  const int wc = wave & 3;     // 0..3 : 48-col group
  f32x4 sacc[2][3];
#pragma unroll
  for (int i = 0; i < 2; ++i)
#pragma unroll
    for (int j = 0; j < 3; ++j) sacc[i][j] = (f32x4)0.0f;

#pragma unroll 2
  for (int ks = 0; ks < 16; ++ks) {        // K = 512 = 16 * 32
    const int kk = ks * 32 + quad * 8;
    short8 af[2];
#pragma unroll
    for (int mt = 0; mt < 2; ++mt)
      af[mt] = *(const short8*)(Qp + (size_t)(t0 + wr * 32 + mt * 16 + col) * D_DIM + kk);
    __builtin_amdgcn_s_setprio(1);
#pragma unroll
    for (int st = 0; st < 3; ++st) {
      int sg = s0 + wc * 48 + st * 16 + col;
      sg = sg < 0 ? 0 : sg;                // clamped keys masked in softmax
      const short8 bfr = *(const short8*)(Kp + (size_t)sg * D_DIM + kk);
#pragma unroll
      for (int mt = 0; mt < 2; ++mt)
        sacc[mt][st] = mfma_bf16(af[mt], bfr, sacc[mt][st]);
    }
    __builtin_amdgcn_s_setprio(0);
  }
  const float scale = 0.04419417382415922f;   // 1/sqrt(512)
#pragma unroll
  for (int mt = 0; mt < 2; ++mt)
#pragma unroll
    for (int st = 0; st < 3; ++st) {
      const int row = wr * 32 + mt * 16 + quad * 4;
      const int c   = wc * 48 + st * 16 + col;
#pragma unroll
      for (int r = 0; r < 4; ++r)
        S[(row + r) * SLD + c] = sacc[mt][st][r] * scale;
    }
  __syncthreads();

  // ---- banded softmax: 8 threads per row, 24 cols each ----
  {
    const int row  = tid >> 3, part = tid & 7;
    const int lo = max(row, HIST - t0);   // j_local >= row and key >= 0
    const int hi = row + HIST;            // causal end (<= 191)
    float* Srow = S + row * SLD;
    const int j0 = part * 24;
    float mx = -3.0e38f;
    for (int j = j0; j < j0 + 24; ++j)
      if (j >= lo && j <= hi) mx = fmaxf(mx, Srow[j]);
    mx = fmaxf(mx, __shfl_xor(mx, 1));
    mx = fmaxf(mx, __shfl_xor(mx, 2));
    mx = fmaxf(mx, __shfl_xor(mx, 4));
    float sum = 0.f;
    for (int j = j0; j < j0 + 24; ++j) {
      if (j >= lo && j <= hi) {
        const float e = __expf(Srow[j] - mx);
        Srow[j] = e;
        sum += e;
      }
    }
    sum += __shfl_xor(sum, 1);
    sum += __shfl_xor(sum, 2);
    sum += __shfl_xor(sum, 4);
    const float inv = 1.0f / sum;
    ushort* Prow = P + row * PLD;
    for (int j = j0; j < j0 + 24; ++j) {
      const float v = (j >= lo && j <= hi) ? Srow[j] * inv : 0.0f;
      Prow[j] = f2bf_bits(v);
    }
  }
  __syncthreads();

  // ---- phase 2: O[64][512] = P[64][192] @ V[192][512], 64 d-cols per wave ----
#pragma unroll
  for (int nt = 0; nt < 4; ++nt) {
    const int d = wave * 64 + nt * 16 + col;
    f32x4 oacc[4];
#pragma unroll
    for (int i = 0; i < 4; ++i) oacc[i] = (f32x4)0.0f;
#pragma unroll
    for (int ksv = 0; ksv < 6; ++ksv) {    // 192 = 6 * 32
      int sg = s0 + ksv * 32 + quad * 8;
      sg = sg < 0 ? 0 : sg;                // P is 0 there
      const short8 bfr = *(const short8*)(Vp + (size_t)d * T_SEQ + sg);
      __builtin_amdgcn_s_setprio(1);
#pragma unroll
      for (int mt = 0; mt < 4; ++mt) {
        const short8 af = *(const short8*)(&P[(mt * 16 + col) * PLD + ksv * 32 + quad * 8]);
        oacc[mt] = mfma_bf16(af, bfr, oacc[mt]);
      }
      __builtin_amdgcn_s_setprio(0);
    }
#pragma unroll
    for (int mt = 0; mt < 4; ++mt) {
      const int mg = t0 + mt * 16 + quad * 4;
#pragma unroll
      for (int r = 0; r < 4; ++r)
        out[((size_t)b * T_SEQ + mg + r) * D_DIM + d] = oacc[mt][r];
    }
  }
}

// ---------------------------------------------------------------------------
extern "C" void kernel_launch(void* const* d_in, const int* in_sizes, int n_in,
                              void* d_out, int out_size, void* d_ws, size_t ws_size,
                              hipStream_t stream) {
  const float* X    = (const float*)d_in[0];   // (B*T, 512) fp32
  const float* W    = (const float*)d_in[1];   // (1536, 512) fp32
  const float* bias = (const float*)d_in[2];   // (1536,) fp32

  // ws layout (bf16/ushort): Xb | Wb | Q | K | Vt   (~68.7 MB total)
  const size_t NX = (size_t)NBATCH * T_SEQ * D_DIM;   // 8388608
  const size_t NW = (size_t)3 * D_DIM * D_DIM;        // 786432
  ushort* Xb = (ushort*)d_ws;
  ushort* Wb = Xb + NX;
  ushort* Qw = Wb + NW;
  ushort* Kw = Qw + NX;
  ushort* Vw = Kw + NX;

  {
    const int nchunks = (int)((NX + NW) / 8);          // 1146880
    cvt_kernel<<<nchunks / 256, 256, 0, stream>>>(X, W, Xb, Wb);
  }

  dim3 g1(128, 12), b1(256);   // M/128 = 128, N/128 = 12
  qkv_gemm_kernel<<<g1, b1, 0, stream>>>(Xb, Wb, bias, Qw, Kw, Vw);

  dim3 g2(NBATCH * (T_SEQ / 64)), b2(512);
  attn_kernel<<<g2, b2, 0, stream>>>(Qw, Kw, Vw, (float*)d_out);
}

// Round 6
// 148.748 us; speedup vs baseline: 1.2793x; 1.0390x over previous
//
#include <hip/hip_runtime.h>
#include <hip/hip_bf16.h>

// SimpleTransformer: qkv = x @ W^T + b ; banded causal attention (window 129).
// B=4, T=4096, D=512, HISTORY=128. Inputs fp32, output fp32 (per reference).
#define T_SEQ 4096
#define D_DIM 512
#define NBATCH 4
#define HIST 128

typedef short short8 __attribute__((ext_vector_type(8)));   // 8 x bf16 bits (4 VGPRs)
typedef float f32x4 __attribute__((ext_vector_type(4)));

static __device__ __forceinline__ f32x4 mfma_bf16(short8 a, short8 b, f32x4 c) {
  return __builtin_amdgcn_mfma_f32_16x16x32_bf16(a, b, c, 0, 0, 0);
}

static __device__ __forceinline__ ushort f2bf_bits(float f) {
  __hip_bfloat16 h = __float2bfloat16(f);
  return *reinterpret_cast<ushort*>(&h);
}

// Async 16B-per-lane global->LDS DMA. LDS dest is wave-uniform base + lane*16.
static __device__ __forceinline__ void gload_lds16(const ushort* g, ushort* l) {
  __builtin_amdgcn_global_load_lds(
      (__attribute__((address_space(1))) void*)g,
      (__attribute__((address_space(3))) void*)l, 16, 0, 0);
}

// ---------------------------------------------------------------------------
// Kernel 0: fp32 -> bf16 conversion of x (8388608) and W (786432), 8 elems/thread.
// ---------------------------------------------------------------------------
__global__ __launch_bounds__(256)
void cvt_kernel(const float* __restrict__ X, const float* __restrict__ W,
                ushort* __restrict__ Xb, ushort* __restrict__ Wb) {
  constexpr size_t NX = (size_t)NBATCH * T_SEQ * D_DIM;   // 8388608
  const size_t off = ((size_t)blockIdx.x * 256 + threadIdx.x) * 8;
  const float* s;
  ushort* d;
  if (off < NX) { s = X + off; d = Xb + off; }
  else          { s = W + (off - NX); d = Wb + (off - NX); }
  const float4 a = *(const float4*)s;
  const float4 b = *(const float4*)(s + 4);
  short8 v;
  v[0] = f2bf_bits(a.x); v[1] = f2bf_bits(a.y);
  v[2] = f2bf_bits(a.z); v[3] = f2bf_bits(a.w);
  v[4] = f2bf_bits(b.x); v[5] = f2bf_bits(b.y);
  v[6] = f2bf_bits(b.z); v[7] = f2bf_bits(b.w);
  *(short8*)d = v;
}

// ---------------------------------------------------------------------------
// Kernel 1: qkv GEMM — UNCHANGED from round 5 (verified: WRITE_SIZE fix, <51us).
// ---------------------------------------------------------------------------
__global__ __launch_bounds__(256, 2)
void qkv_gemm_kernel(const ushort* __restrict__ X,
                     const ushort* __restrict__ W,
                     const float* __restrict__ bias,
                     ushort* __restrict__ Qo,
                     ushort* __restrict__ Ko,
                     ushort* __restrict__ Vt) {
  constexpr int BK = 64, KD = D_DIM;
  constexpr int NT = KD / BK;                       // 8 K-steps
  __shared__ __align__(16) ushort sA[2][128 * BK];  // 2 x 16 KB
  __shared__ __align__(16) ushort sB[2][128 * BK];  // 2 x 16 KB

  const int tid  = threadIdx.x;
  const int wave = tid >> 6, lane = tid & 63;
  const int col  = lane & 15, quad = lane >> 4;
  const int m0 = blockIdx.x * 128;
  const int n0 = blockIdx.y * 128;
  const int wm = (wave >> 1) * 64, wn = (wave & 1) * 64;

  const ushort* gA[4];
  const ushort* gB[4];
#pragma unroll
  for (int j = 0; j < 4; ++j) {
    const int c  = wave * 256 + j * 64 + lane;
    const int m  = c >> 3;
    const int kq = (c & 7) ^ (m & 7);
    gA[j] = X + (size_t)(m0 + m) * KD + kq * 8;
    gB[j] = W + (size_t)(n0 + m) * KD + kq * 8;
  }

  auto stage = [&](int buf, int t) {
#pragma unroll
    for (int j = 0; j < 4; ++j) {
      gload_lds16(gA[j] + t * BK, &sA[buf][(wave * 256 + j * 64) * 8]);
      gload_lds16(gB[j] + t * BK, &sB[buf][(wave * 256 + j * 64) * 8]);
    }
  };

  f32x4 acc[4][4];
#pragma unroll
  for (int i = 0; i < 4; ++i)
#pragma unroll
    for (int j = 0; j < 4; ++j) acc[i][j] = (f32x4)0.0f;

  stage(0, 0);
  stage(1, 1);

#pragma unroll
  for (int t = 0; t < NT; ++t) {
    if (t < NT - 1) asm volatile("s_waitcnt vmcnt(8)" ::: "memory");
    else            asm volatile("s_waitcnt vmcnt(0)" ::: "memory");
    __builtin_amdgcn_s_barrier();        // tile t visible to all waves

    const ushort* cA = sA[t & 1];
    const ushort* cB = sB[t & 1];
    short8 af[2][4], bf[2][4];
#pragma unroll
    for (int ks = 0; ks < 2; ++ks) {
      const int kq = ks * 4 + quad;
#pragma unroll
      for (int mt = 0; mt < 4; ++mt) {
        const int m = wm + mt * 16 + col;
        af[ks][mt] = *(const short8*)(&cA[(m * 8 + (kq ^ (m & 7))) * 8]);
        const int n = wn + mt * 16 + col;
        bf[ks][mt] = *(const short8*)(&cB[(n * 8 + (kq ^ (n & 7))) * 8]);
      }
    }
    asm volatile("s_waitcnt lgkmcnt(0)" ::: "memory");  // reads done (in regs)
    __builtin_amdgcn_s_barrier();        // all waves done reading buf[t&1]

    if (t + 2 < NT) stage(t & 1, t + 2); // overwrite safe; not waited

    __builtin_amdgcn_s_setprio(1);
#pragma unroll
    for (int ks = 0; ks < 2; ++ks)
#pragma unroll
      for (int mt = 0; mt < 4; ++mt)
#pragma unroll
        for (int nt = 0; nt < 4; ++nt)
          acc[mt][nt] = mfma_bf16(af[ks][mt], bf[ks][nt], acc[mt][nt]);
    __builtin_amdgcn_s_setprio(0);
  }

  // ---- epilogue: per-wave 64x64 bf16 tile via LDS, 16B/lane stores ----
  ushort* eL = &sA[0][0] + wave * 4096;
  const int region = n0 >> 9;   // 0=Q, 1=K, 2=V

  if (region < 2) {
#pragma unroll
    for (int nt = 0; nt < 4; ++nt) {
      const float bv = bias[n0 + wn + nt * 16 + col];
      const int cl = nt * 16 + col;
#pragma unroll
      for (int mt = 0; mt < 4; ++mt) {
        const int rb = mt * 16 + quad * 4;
#pragma unroll
        for (int r = 0; r < 4; ++r) {
          const int R = rb + r;
          eL[R * 64 + (((cl >> 3) ^ (R & 7)) * 8) + (cl & 7)] =
              f2bf_bits(acc[mt][nt][r] + bv);
        }
      }
    }
    ushort* __restrict__ Out = (region == 0) ? Qo : Ko;
    const int rgrp = lane >> 3, cch = lane & 7;
    const int phys = cch ^ rgrp;
    const int dbase = (n0 & (D_DIM - 1)) + wn + cch * 8;
#pragma unroll
    for (int j = 0; j < 8; ++j) {
      const int R = j * 8 + rgrp;
      const short8 v = *(const short8*)(&eL[R * 64 + phys * 8]);
      *(short8*)(&Out[(size_t)(m0 + wm + R) * D_DIM + dbase]) = v;
    }
  } else {
#pragma unroll
    for (int nt = 0; nt < 4; ++nt) {
      const float bv = bias[n0 + wn + nt * 16 + col];
      const int dl = nt * 16 + col;
#pragma unroll
      for (int mt = 0; mt < 4; ++mt) {
        const int rb = mt * 16 + quad * 4;
#pragma unroll
        for (int r = 0; r < 4; ++r) {
          const int tl = rb + r;
          eL[dl * 64 + (((tl >> 3) ^ (dl & 7)) * 8) + (tl & 7)] =
              f2bf_bits(acc[mt][nt][r] + bv);
        }
      }
    }
    const int rgrp = lane >> 3, cch = lane & 7;
    const int phys = cch ^ rgrp;
    const int mr0 = m0 + wm;
    const int bb  = mr0 >> 12;
    const int tt0 = (mr0 & (T_SEQ - 1)) + cch * 8;
#pragma unroll
    for (int j = 0; j < 8; ++j) {
      const int dl = j * 8 + rgrp;
      const short8 v = *(const short8*)(&eL[dl * 64 + phys * 8]);
      const int d = (n0 & (D_DIM - 1)) + wn + dl;
      *(short8*)(&Vt[((size_t)bb * D_DIM + d) * T_SEQ + tt0]) = v;
    }
  }
}

// ---------------------------------------------------------------------------
// Kernel 2: banded attention. 256 blocks x 512 thr (grid-capped 1 blk/CU).
//   Latency-bound fixes this round:
//   - XCD swizzle: each XCD owns 32 CONSECUTIVE query tiles -> overlapping
//     K/V windows (128/192 shared keys) become L2 hits.
//   - launch_bounds(512,2): VGPR cap 256 (was 52) so loads can stay in flight.
//   - QK^T: explicit depth-4 register prefetch (static ks&3 slots, 15 loads
//     in flight ~ 3 iters of latency cover).
//   - PV: V frags double-buffered; nt=0 V loads issued BEFORE the softmax
//     barrier; barriers are lgkmcnt(0)+raw s_barrier (no vmcnt drain) so
//     those loads fly across the softmax phase (T14).
//   - P writes packed as uint (halves 8-way bank-conflict instructions).
// ---------------------------------------------------------------------------
__global__ __launch_bounds__(512, 2)
void attn_kernel(const ushort* __restrict__ Qb,
                 const ushort* __restrict__ Kb,
                 const ushort* __restrict__ Vtb,
                 float* __restrict__ out) {
  constexpr int SLD = 193;   // fp32 stride (odd) -> conflict-free softmax sweeps
  constexpr int PLD = 200;   // bf16 stride, 400B rows (16B aligned)
  __shared__ float  S[64 * SLD];   // 49408 B
  __shared__ ushort P[64 * PLD];   // 25600 B

  const int tid  = threadIdx.x;
  const int wave = tid >> 6, lane = tid & 63;
  const int col  = lane & 15, quad = lane >> 4;
  // XCD-aware bijective swizzle (grid 256, 8 XCDs -> 32 consecutive tiles/XCD)
  const int l  = (blockIdx.x & 7) * 32 + (blockIdx.x >> 3);
  const int b  = l >> 6;
  const int t0 = (l & 63) * 64;
  const int s0 = t0 - HIST;

  const ushort* Qp = Qb  + (size_t)b * T_SEQ * D_DIM;
  const ushort* Kp = Kb  + (size_t)b * T_SEQ * D_DIM;
  const ushort* Vp = Vtb + (size_t)b * D_DIM * T_SEQ;

  // ---- phase 1: S[64][192] = Q K^T ----
  const int wr = wave >> 2;    // 0..1 : 32-row group
  const int wc = wave & 3;     // 0..3 : 48-col group
  const ushort* qp0 = Qp + (size_t)(t0 + wr * 32 + col) * D_DIM;
  const ushort* qp1 = qp0 + 16 * D_DIM;
  const ushort* kp[3];
#pragma unroll
  for (int st = 0; st < 3; ++st) {
    int sg = s0 + wc * 48 + st * 16 + col;
    sg = sg < 0 ? 0 : sg;                // clamped keys masked in softmax
    kp[st] = Kp + (size_t)sg * D_DIM;
  }

  f32x4 sacc[2][3];
#pragma unroll
  for (int i = 0; i < 2; ++i)
#pragma unroll
    for (int j = 0; j < 3; ++j) sacc[i][j] = (f32x4)0.0f;

  constexpr int PD = 4;                  // prefetch depth (5 loads/iter -> 15 in flight)
  short8 qf[PD][2], kf[PD][3];
#pragma unroll
  for (int d = 0; d < PD; ++d) {
    const int kk = d * 32 + quad * 8;
    qf[d][0] = *(const short8*)(qp0 + kk);
    qf[d][1] = *(const short8*)(qp1 + kk);
#pragma unroll
    for (int st = 0; st < 3; ++st)
      kf[d][st] = *(const short8*)(kp[st] + kk);
  }
#pragma unroll
  for (int ks = 0; ks < 16; ++ks) {      // K = 512 = 16 * 32
    const int slot = ks & 3;             // compile-time (fully unrolled)
    __builtin_amdgcn_s_setprio(1);
#pragma unroll
    for (int st = 0; st < 3; ++st) {
      sacc[0][st] = mfma_bf16(qf[slot][0], kf[slot][st], sacc[0][st]);
      sacc[1][st] = mfma_bf16(qf[slot][1], kf[slot][st], sacc[1][st]);
    }
    __builtin_amdgcn_s_setprio(0);
    if (ks + PD < 16) {
      const int kk = (ks + PD) * 32 + quad * 8;
      qf[slot][0] = *(const short8*)(qp0 + kk);
      qf[slot][1] = *(const short8*)(qp1 + kk);
#pragma unroll
      for (int st = 0; st < 3; ++st)
        kf[slot][st] = *(const short8*)(kp[st] + kk);
    }
  }
  const float scale = 0.04419417382415922f;   // 1/sqrt(512)
#pragma unroll
  for (int mt = 0; mt < 2; ++mt)
#pragma unroll
    for (int st = 0; st < 3; ++st) {
      const int row = wr * 32 + mt * 16 + quad * 4;
      const int c   = wc * 48 + st * 16 + col;
#pragma unroll
      for (int r = 0; r < 4; ++r)
        S[(row + r) * SLD + c] = sacc[mt][st][r] * scale;
    }

  // Issue nt=0 V loads NOW (independent of softmax); they fly across the
  // barriers below because we never drain vmcnt.
  const ushort* vbase = Vp + (size_t)(wave * 64 + col) * T_SEQ;
  short8 vf[2][6];
#pragma unroll
  for (int k = 0; k < 6; ++k) {
    int sg = s0 + k * 32 + quad * 8;
    sg = sg < 0 ? 0 : sg;                // P is 0 there
    vf[0][k] = *(const short8*)(vbase + sg);
  }

  asm volatile("s_waitcnt lgkmcnt(0)" ::: "memory");  // S stores visible
  __builtin_amdgcn_s_barrier();

  // ---- banded softmax: 8 threads per row, 24 cols each ----
  {
    const int row  = tid >> 3, part = tid & 7;
    const int lo = max(row, HIST - t0);   // j_local >= row and key >= 0
    const int hi = row + HIST;            // causal end (<= 191)
    float* Srow = S + row * SLD;
    const int j0 = part * 24;
    float mx = -3.0e38f;
    for (int j = j0; j < j0 + 24; ++j)
      if (j >= lo && j <= hi) mx = fmaxf(mx, Srow[j]);
    mx = fmaxf(mx, __shfl_xor(mx, 1));
    mx = fmaxf(mx, __shfl_xor(mx, 2));
    mx = fmaxf(mx, __shfl_xor(mx, 4));
    float sum = 0.f;
    for (int j = j0; j < j0 + 24; ++j) {
      if (j >= lo && j <= hi) {
        const float e = __expf(Srow[j] - mx);
        Srow[j] = e;
        sum += e;
      }
    }
    sum += __shfl_xor(sum, 1);
    sum += __shfl_xor(sum, 2);
    sum += __shfl_xor(sum, 4);
    const float inv = 1.0f / sum;
    uint* Prow32 = (uint*)(P + row * PLD);   // 400B rows -> 4B aligned
#pragma unroll
    for (int i = 0; i < 12; ++i) {
      const int j = j0 + 2 * i;
      const float v0 = (j     >= lo && j     <= hi) ? Srow[j]     * inv : 0.0f;
      const float v1 = (j + 1 >= lo && j + 1 <= hi) ? Srow[j + 1] * inv : 0.0f;
      Prow32[part * 12 + i] = (uint)f2bf_bits(v0) | ((uint)f2bf_bits(v1) << 16);
    }
  }
  asm volatile("s_waitcnt lgkmcnt(0)" ::: "memory");  // P writes visible
  __builtin_amdgcn_s_barrier();

  // ---- phase 2: O[64][512] = P[64][192] @ V[192][512], 64 d-cols/wave ----
#pragma unroll
  for (int nt = 0; nt < 4; ++nt) {
    const int cb = nt & 1;
    if (nt < 3) {                        // prefetch next nt's V frags
#pragma unroll
      for (int k = 0; k < 6; ++k) {
        int sg = s0 + k * 32 + quad * 8;
        sg = sg < 0 ? 0 : sg;
        vf[cb ^ 1][k] = *(const short8*)(vbase + (size_t)(nt + 1) * 16 * T_SEQ + sg);
      }
    }
    f32x4 oacc[4];
#pragma unroll
    for (int i = 0; i < 4; ++i) oacc[i] = (f32x4)0.0f;
#pragma unroll
    for (int k = 0; k < 6; ++k) {        // 192 = 6 * 32
      __builtin_amdgcn_s_setprio(1);
#pragma unroll
      for (int mt = 0; mt < 4; ++mt) {
        const short8 af = *(const short8*)(&P[(mt * 16 + col) * PLD + k * 32 + quad * 8]);
        oacc[mt] = mfma_bf16(af, vf[cb][k], oacc[mt]);
      }
      __builtin_amdgcn_s_setprio(0);
    }
    const int d = wave * 64 + nt * 16 + col;
#pragma unroll
    for (int mt = 0; mt < 4; ++mt) {
      const int mg = t0 + mt * 16 + quad * 4;
#pragma unroll
      for (int r = 0; r < 4; ++r)
        out[((size_t)b * T_SEQ + mg + r) * D_DIM + d] = oacc[mt][r];
    }
  }
}

// ---------------------------------------------------------------------------
extern "C" void kernel_launch(void* const* d_in, const int* in_sizes, int n_in,
                              void* d_out, int out_size, void* d_ws, size_t ws_size,
                              hipStream_t stream) {
  const float* X    = (const float*)d_in[0];   // (B*T, 512) fp32
  const float* W    = (const float*)d_in[1];   // (1536, 512) fp32
  const float* bias = (const float*)d_in[2];   // (1536,) fp32

  // ws layout (bf16/ushort): Xb | Wb | Q | K | Vt   (~68.7 MB total)
  const size_t NX = (size_t)NBATCH * T_SEQ * D_DIM;   // 8388608
  const size_t NW = (size_t)3 * D_DIM * D_DIM;        // 786432
  ushort* Xb = (ushort*)d_ws;
  ushort* Wb = Xb + NX;
  ushort* Qw = Wb + NW;
  ushort* Kw = Qw + NX;
  ushort* Vw = Kw + NX;

  {
    const int nchunks = (int)((NX + NW) / 8);          // 1146880
    cvt_kernel<<<nchunks / 256, 256, 0, stream>>>(X, W, Xb, Wb);
  }

  dim3 g1(128, 12), b1(256);   // M/128 = 128, N/128 = 12
  qkv_gemm_kernel<<<g1, b1, 0, stream>>>(Xb, Wb, bias, Qw, Kw, Vw);

  dim3 g2(NBATCH * (T_SEQ / 64)), b2(512);
  attn_kernel<<<g2, b2, 0, stream>>>(Qw, Kw, Vw, (float*)d_out);
}

// Round 7
// 147.569 us; speedup vs baseline: 1.2895x; 1.0080x over previous
//
#include <hip/hip_runtime.h>
#include <hip/hip_bf16.h>

// SimpleTransformer: qkv = x @ W^T + b ; banded causal attention (window 129).
// B=4, T=4096, D=512, HISTORY=128. Inputs fp32, output fp32 (per reference).
#define T_SEQ 4096
#define D_DIM 512
#define NBATCH 4
#define HIST 128

typedef short short8 __attribute__((ext_vector_type(8)));   // 8 x bf16 bits (4 VGPRs)
typedef float f32x4 __attribute__((ext_vector_type(4)));

static __device__ __forceinline__ f32x4 mfma_bf16(short8 a, short8 b, f32x4 c) {
  return __builtin_amdgcn_mfma_f32_16x16x32_bf16(a, b, c, 0, 0, 0);
}

static __device__ __forceinline__ ushort f2bf_bits(float f) {
  __hip_bfloat16 h = __float2bfloat16(f);
  return *reinterpret_cast<ushort*>(&h);
}

// Async 16B-per-lane global->LDS DMA. LDS dest is wave-uniform base + lane*16.
static __device__ __forceinline__ void gload_lds16(const ushort* g, ushort* l) {
  __builtin_amdgcn_global_load_lds(
      (__attribute__((address_space(1))) void*)g,
      (__attribute__((address_space(3))) void*)l, 16, 0, 0);
}

// ---------------------------------------------------------------------------
// Kernel 0: fp32 -> bf16 conversion, 16 elems (64B read / 32B write) per thread.
// ---------------------------------------------------------------------------
__global__ __launch_bounds__(256)
void cvt_kernel(const float* __restrict__ X, const float* __restrict__ W,
                ushort* __restrict__ Xb, ushort* __restrict__ Wb) {
  constexpr size_t NX = (size_t)NBATCH * T_SEQ * D_DIM;   // 8388608
  const size_t off = ((size_t)blockIdx.x * 256 + threadIdx.x) * 16;
  const float* s;
  ushort* d;
  if (off < NX) { s = X + off; d = Xb + off; }     // regions 16-aligned: no straddle
  else          { s = W + (off - NX); d = Wb + (off - NX); }
#pragma unroll
  for (int h = 0; h < 2; ++h) {
    const float4 a = *(const float4*)(s + h * 8);
    const float4 b = *(const float4*)(s + h * 8 + 4);
    short8 v;
    v[0] = f2bf_bits(a.x); v[1] = f2bf_bits(a.y);
    v[2] = f2bf_bits(a.z); v[3] = f2bf_bits(a.w);
    v[4] = f2bf_bits(b.x); v[5] = f2bf_bits(b.y);
    v[6] = f2bf_bits(b.z); v[7] = f2bf_bits(b.w);
    *(short8*)(d + h * 8) = v;
  }
}

// ---------------------------------------------------------------------------
// Kernel 1: qkv[m][n] = sum_k X[m][k] * W[n][k] + bias[n]   (bf16 in, fp32 acc)
//   M = 16384, N = 1536, K = 512. Tile 128x128, BK=64, 256 threads (2x2 waves).
//   NEW: linear 1536-block grid with XCD-chunked bijective swizzle (T1):
//   XCD c owns logical blocks [c*192,(c+1)*192), ordered n-fastest, so the 12
//   blocks sharing one 128-row X-tile run on the SAME XCD (X-tile fetched
//   once per L2, reused 12x; W 1.5MB fully L2-resident). Old grid scattered
//   them across all 8 XCDs.
//   K-loop: 2-deep pipeline, raw s_barrier + counted s_waitcnt vmcnt(8).
//   Epilogue: per-wave 64x64 bf16 tile via LDS, 16B/lane stores (WRITE fix).
// ---------------------------------------------------------------------------
__global__ __launch_bounds__(256, 2)
void qkv_gemm_kernel(const ushort* __restrict__ X,
                     const ushort* __restrict__ W,
                     const float* __restrict__ bias,
                     ushort* __restrict__ Qo,
                     ushort* __restrict__ Ko,
                     ushort* __restrict__ Vt) {
  constexpr int BK = 64, KD = D_DIM;
  constexpr int NT = KD / BK;                       // 8 K-steps
  __shared__ __align__(16) ushort sA[2][128 * BK];  // 2 x 16 KB
  __shared__ __align__(16) ushort sB[2][128 * BK];  // 2 x 16 KB

  const int tid  = threadIdx.x;
  const int wave = tid >> 6, lane = tid & 63;
  const int col  = lane & 15, quad = lane >> 4;
  // XCD-chunked swizzle: 1536 blocks, 8 XCDs, 192 logical/XCD, n fastest.
  const int lb = (blockIdx.x & 7) * 192 + (blockIdx.x >> 3);
  const int m0 = (lb / 12) * 128;
  const int n0 = (lb % 12) * 128;
  const int wm = (wave >> 1) * 64, wn = (wave & 1) * 64;

  const ushort* gA[4];
  const ushort* gB[4];
#pragma unroll
  for (int j = 0; j < 4; ++j) {
    const int c  = wave * 256 + j * 64 + lane;
    const int m  = c >> 3;
    const int kq = (c & 7) ^ (m & 7);
    gA[j] = X + (size_t)(m0 + m) * KD + kq * 8;
    gB[j] = W + (size_t)(n0 + m) * KD + kq * 8;
  }

  auto stage = [&](int buf, int t) {
#pragma unroll
    for (int j = 0; j < 4; ++j) {
      gload_lds16(gA[j] + t * BK, &sA[buf][(wave * 256 + j * 64) * 8]);
      gload_lds16(gB[j] + t * BK, &sB[buf][(wave * 256 + j * 64) * 8]);
    }
  };

  f32x4 acc[4][4];
#pragma unroll
  for (int i = 0; i < 4; ++i)
#pragma unroll
    for (int j = 0; j < 4; ++j) acc[i][j] = (f32x4)0.0f;

  stage(0, 0);
  stage(1, 1);

#pragma unroll
  for (int t = 0; t < NT; ++t) {
    if (t < NT - 1) asm volatile("s_waitcnt vmcnt(8)" ::: "memory");
    else            asm volatile("s_waitcnt vmcnt(0)" ::: "memory");
    __builtin_amdgcn_s_barrier();        // tile t visible to all waves

    const ushort* cA = sA[t & 1];
    const ushort* cB = sB[t & 1];
    short8 af[2][4], bf[2][4];
#pragma unroll
    for (int ks = 0; ks < 2; ++ks) {
      const int kq = ks * 4 + quad;
#pragma unroll
      for (int mt = 0; mt < 4; ++mt) {
        const int m = wm + mt * 16 + col;
        af[ks][mt] = *(const short8*)(&cA[(m * 8 + (kq ^ (m & 7))) * 8]);
        const int n = wn + mt * 16 + col;
        bf[ks][mt] = *(const short8*)(&cB[(n * 8 + (kq ^ (n & 7))) * 8]);
      }
    }
    asm volatile("s_waitcnt lgkmcnt(0)" ::: "memory");  // reads done (in regs)
    __builtin_amdgcn_s_barrier();        // all waves done reading buf[t&1]

    if (t + 2 < NT) stage(t & 1, t + 2); // overwrite safe; not waited

    __builtin_amdgcn_s_setprio(1);
#pragma unroll
    for (int ks = 0; ks < 2; ++ks)
#pragma unroll
      for (int mt = 0; mt < 4; ++mt)
#pragma unroll
        for (int nt = 0; nt < 4; ++nt)
          acc[mt][nt] = mfma_bf16(af[ks][mt], bf[ks][nt], acc[mt][nt]);
    __builtin_amdgcn_s_setprio(0);
  }

  // ---- epilogue: per-wave 64x64 bf16 tile via LDS, 16B/lane stores ----
  ushort* eL = &sA[0][0] + wave * 4096;
  const int region = n0 >> 9;   // 0=Q, 1=K, 2=V

  if (region < 2) {
#pragma unroll
    for (int nt = 0; nt < 4; ++nt) {
      const float bv = bias[n0 + wn + nt * 16 + col];
      const int cl = nt * 16 + col;
#pragma unroll
      for (int mt = 0; mt < 4; ++mt) {
        const int rb = mt * 16 + quad * 4;
#pragma unroll
        for (int r = 0; r < 4; ++r) {
          const int R = rb + r;
          eL[R * 64 + (((cl >> 3) ^ (R & 7)) * 8) + (cl & 7)] =
              f2bf_bits(acc[mt][nt][r] + bv);
        }
      }
    }
    ushort* __restrict__ Out = (region == 0) ? Qo : Ko;
    const int rgrp = lane >> 3, cch = lane & 7;
    const int phys = cch ^ rgrp;
    const int dbase = (n0 & (D_DIM - 1)) + wn + cch * 8;
#pragma unroll
    for (int j = 0; j < 8; ++j) {
      const int R = j * 8 + rgrp;
      const short8 v = *(const short8*)(&eL[R * 64 + phys * 8]);
      *(short8*)(&Out[(size_t)(m0 + wm + R) * D_DIM + dbase]) = v;
    }
  } else {
#pragma unroll
    for (int nt = 0; nt < 4; ++nt) {
      const float bv = bias[n0 + wn + nt * 16 + col];
      const int dl = nt * 16 + col;
#pragma unroll
      for (int mt = 0; mt < 4; ++mt) {
        const int rb = mt * 16 + quad * 4;
#pragma unroll
        for (int r = 0; r < 4; ++r) {
          const int tl = rb + r;
          eL[dl * 64 + (((tl >> 3) ^ (dl & 7)) * 8) + (tl & 7)] =
              f2bf_bits(acc[mt][nt][r] + bv);
        }
      }
    }
    const int rgrp = lane >> 3, cch = lane & 7;
    const int phys = cch ^ rgrp;
    const int mr0 = m0 + wm;
    const int bb  = mr0 >> 12;
    const int tt0 = (mr0 & (T_SEQ - 1)) + cch * 8;
#pragma unroll
    for (int j = 0; j < 8; ++j) {
      const int dl = j * 8 + rgrp;
      const short8 v = *(const short8*)(&eL[dl * 64 + phys * 8]);
      const int d = (n0 & (D_DIM - 1)) + wn + dl;
      *(short8*)(&Vt[((size_t)bb * D_DIM + d) * T_SEQ + tt0]) = v;
    }
  }
}

// ---------------------------------------------------------------------------
// Kernel 2: banded attention — UNCHANGED from round 6 (verified: 51.6 -> <41us).
// ---------------------------------------------------------------------------
__global__ __launch_bounds__(512, 2)
void attn_kernel(const ushort* __restrict__ Qb,
                 const ushort* __restrict__ Kb,
                 const ushort* __restrict__ Vtb,
                 float* __restrict__ out) {
  constexpr int SLD = 193;   // fp32 stride (odd) -> conflict-free softmax sweeps
  constexpr int PLD = 200;   // bf16 stride, 400B rows (16B aligned)
  __shared__ float  S[64 * SLD];   // 49408 B
  __shared__ ushort P[64 * PLD];   // 25600 B

  const int tid  = threadIdx.x;
  const int wave = tid >> 6, lane = tid & 63;
  const int col  = lane & 15, quad = lane >> 4;
  // XCD-aware bijective swizzle (grid 256, 8 XCDs -> 32 consecutive tiles/XCD)
  const int l  = (blockIdx.x & 7) * 32 + (blockIdx.x >> 3);
  const int b  = l >> 6;
  const int t0 = (l & 63) * 64;
  const int s0 = t0 - HIST;

  const ushort* Qp = Qb  + (size_t)b * T_SEQ * D_DIM;
  const ushort* Kp = Kb  + (size_t)b * T_SEQ * D_DIM;
  const ushort* Vp = Vtb + (size_t)b * D_DIM * T_SEQ;

  // ---- phase 1: S[64][192] = Q K^T ----
  const int wr = wave >> 2;    // 0..1 : 32-row group
  const int wc = wave & 3;     // 0..3 : 48-col group
  const ushort* qp0 = Qp + (size_t)(t0 + wr * 32 + col) * D_DIM;
  const ushort* qp1 = qp0 + 16 * D_DIM;
  const ushort* kp[3];
#pragma unroll
  for (int st = 0; st < 3; ++st) {
    int sg = s0 + wc * 48 + st * 16 + col;
    sg = sg < 0 ? 0 : sg;                // clamped keys masked in softmax
    kp[st] = Kp + (size_t)sg * D_DIM;
  }

  f32x4 sacc[2][3];
#pragma unroll
  for (int i = 0; i < 2; ++i)
#pragma unroll
    for (int j = 0; j < 3; ++j) sacc[i][j] = (f32x4)0.0f;

  constexpr int PD = 4;                  // prefetch depth (5 loads/iter -> 15 in flight)
  short8 qf[PD][2], kf[PD][3];
#pragma unroll
  for (int d = 0; d < PD; ++d) {
    const int kk = d * 32 + quad * 8;
    qf[d][0] = *(const short8*)(qp0 + kk);
    qf[d][1] = *(const short8*)(qp1 + kk);
#pragma unroll
    for (int st = 0; st < 3; ++st)
      kf[d][st] = *(const short8*)(kp[st] + kk);
  }
#pragma unroll
  for (int ks = 0; ks < 16; ++ks) {      // K = 512 = 16 * 32
    const int slot = ks & 3;             // compile-time (fully unrolled)
    __builtin_amdgcn_s_setprio(1);
#pragma unroll
    for (int st = 0; st < 3; ++st) {
      sacc[0][st] = mfma_bf16(qf[slot][0], kf[slot][st], sacc[0][st]);
      sacc[1][st] = mfma_bf16(qf[slot][1], kf[slot][st], sacc[1][st]);
    }
    __builtin_amdgcn_s_setprio(0);
    if (ks + PD < 16) {
      const int kk = (ks + PD) * 32 + quad * 8;
      qf[slot][0] = *(const short8*)(qp0 + kk);
      qf[slot][1] = *(const short8*)(qp1 + kk);
#pragma unroll
      for (int st = 0; st < 3; ++st)
        kf[slot][st] = *(const short8*)(kp[st] + kk);
    }
  }
  const float scale = 0.04419417382415922f;   // 1/sqrt(512)
#pragma unroll
  for (int mt = 0; mt < 2; ++mt)
#pragma unroll
    for (int st = 0; st < 3; ++st) {
      const int row = wr * 32 + mt * 16 + quad * 4;
      const int c   = wc * 48 + st * 16 + col;
#pragma unroll
      for (int r = 0; r < 4; ++r)
        S[(row + r) * SLD + c] = sacc[mt][st][r] * scale;
    }

  // Issue nt=0 V loads NOW (independent of softmax); they fly across the
  // barriers below because we never drain vmcnt.
  const ushort* vbase = Vp + (size_t)(wave * 64 + col) * T_SEQ;
  short8 vf[2][6];
#pragma unroll
  for (int k = 0; k < 6; ++k) {
    int sg = s0 + k * 32 + quad * 8;
    sg = sg < 0 ? 0 : sg;                // P is 0 there
    vf[0][k] = *(const short8*)(vbase + sg);
  }

  asm volatile("s_waitcnt lgkmcnt(0)" ::: "memory");  // S stores visible
  __builtin_amdgcn_s_barrier();

  // ---- banded softmax: 8 threads per row, 24 cols each ----
  {
    const int row  = tid >> 3, part = tid & 7;
    const int lo = max(row, HIST - t0);   // j_local >= row and key >= 0
    const int hi = row + HIST;            // causal end (<= 191)
    float* Srow = S + row * SLD;
    const int j0 = part * 24;
    float mx = -3.0e38f;
    for (int j = j0; j < j0 + 24; ++j)
      if (j >= lo && j <= hi) mx = fmaxf(mx, Srow[j]);
    mx = fmaxf(mx, __shfl_xor(mx, 1));
    mx = fmaxf(mx, __shfl_xor(mx, 2));
    mx = fmaxf(mx, __shfl_xor(mx, 4));
    float sum = 0.f;
    for (int j = j0; j < j0 + 24; ++j) {
      if (j >= lo && j <= hi) {
        const float e = __expf(Srow[j] - mx);
        Srow[j] = e;
        sum += e;
      }
    }
    sum += __shfl_xor(sum, 1);
    sum += __shfl_xor(sum, 2);
    sum += __shfl_xor(sum, 4);
    const float inv = 1.0f / sum;
    uint* Prow32 = (uint*)(P + row * PLD);   // 400B rows -> 4B aligned
#pragma unroll
    for (int i = 0; i < 12; ++i) {
      const int j = j0 + 2 * i;
      const float v0 = (j     >= lo && j     <= hi) ? Srow[j]     * inv : 0.0f;
      const float v1 = (j + 1 >= lo && j + 1 <= hi) ? Srow[j + 1] * inv : 0.0f;
      Prow32[part * 12 + i] = (uint)f2bf_bits(v0) | ((uint)f2bf_bits(v1) << 16);
    }
  }
  asm volatile("s_waitcnt lgkmcnt(0)" ::: "memory");  // P writes visible
  __builtin_amdgcn_s_barrier();

  // ---- phase 2: O[64][512] = P[64][192] @ V[192][512], 64 d-cols/wave ----
#pragma unroll
  for (int nt = 0; nt < 4; ++nt) {
    const int cb = nt & 1;
    if (nt < 3) {                        // prefetch next nt's V frags
#pragma unroll
      for (int k = 0; k < 6; ++k) {
        int sg = s0 + k * 32 + quad * 8;
        sg = sg < 0 ? 0 : sg;
        vf[cb ^ 1][k] = *(const short8*)(vbase + (size_t)(nt + 1) * 16 * T_SEQ + sg);
      }
    }
    f32x4 oacc[4];
#pragma unroll
    for (int i = 0; i < 4; ++i) oacc[i] = (f32x4)0.0f;
#pragma unroll
    for (int k = 0; k < 6; ++k) {        // 192 = 6 * 32
      __builtin_amdgcn_s_setprio(1);
#pragma unroll
      for (int mt = 0; mt < 4; ++mt) {
        const short8 af = *(const short8*)(&P[(mt * 16 + col) * PLD + k * 32 + quad * 8]);
        oacc[mt] = mfma_bf16(af, vf[cb][k], oacc[mt]);
      }
      __builtin_amdgcn_s_setprio(0);
    }
    const int d = wave * 64 + nt * 16 + col;
#pragma unroll
    for (int mt = 0; mt < 4; ++mt) {
      const int mg = t0 + mt * 16 + quad * 4;
#pragma unroll
      for (int r = 0; r < 4; ++r)
        out[((size_t)b * T_SEQ + mg + r) * D_DIM + d] = oacc[mt][r];
    }
  }
}

// ---------------------------------------------------------------------------
extern "C" void kernel_launch(void* const* d_in, const int* in_sizes, int n_in,
                              void* d_out, int out_size, void* d_ws, size_t ws_size,
                              hipStream_t stream) {
  const float* X    = (const float*)d_in[0];   // (B*T, 512) fp32
  const float* W    = (const float*)d_in[1];   // (1536, 512) fp32
  const float* bias = (const float*)d_in[2];   // (1536,) fp32

  // ws layout (bf16/ushort): Xb | Wb | Q | K | Vt   (~68.7 MB total)
  const size_t NX = (size_t)NBATCH * T_SEQ * D_DIM;   // 8388608
  const size_t NW = (size_t)3 * D_DIM * D_DIM;        // 786432
  ushort* Xb = (ushort*)d_ws;
  ushort* Wb = Xb + NX;
  ushort* Qw = Wb + NW;
  ushort* Kw = Qw + NX;
  ushort* Vw = Kw + NX;

  {
    const int nchunks16 = (int)((NX + NW) / 16);       // 573440
    cvt_kernel<<<nchunks16 / 256, 256, 0, stream>>>(X, W, Xb, Wb);
  }

  dim3 g1(1536), b1(256);   // linear grid; XCD-chunked swizzle in-kernel
  qkv_gemm_kernel<<<g1, b1, 0, stream>>>(Xb, Wb, bias, Qw, Kw, Vw);

  dim3 g2(NBATCH * (T_SEQ / 64)), b2(512);
  attn_kernel<<<g2, b2, 0, stream>>>(Qw, Kw, Vw, (float*)d_out);
}